// Round 4
// baseline (1583.740 us; speedup 1.0000x reference)
//
#include <hip/hip_runtime.h>

#define A_ 8
#define B_ 32768
#define OBS_ 128
#define ACT_ 32
#define F_ 160          // OBS + ACT
#define E_ 128
#define H_ 4
#define D_ 32

// ---- workspace layout (floats) — total ~1.21 MB ----
#define WS_GSUM 0
#define WS_GSQ  1280
#define WS_MEAN 2560
#define WS_RSTD 3840
#define WS_WG2  5120                  // 8*160*128 = 163840
#define WS_BG2  (WS_WG2 + 163840)     // 1024
#define WS_WS2  (WS_BG2 + 1024)       // 131072
#define WS_BS2  (WS_WS2 + 131072)     // 1024
#define WS_TOTAL (WS_BS2 + 1024)      // 302080 floats

// ---- fused-kernel LDS layout (floats), phase-overlaid ----
// 0......8192    X head (phase1-2) -> q (phase3-4) -> v (phase5-6)
// 8192...10240   X tail (phase1-2) -> alpha (phase4-6) -> qv (phase8-9)
// 10240..18432   e (phase2-5) -> h1 (phase7-8)
// 18432..26624   s (phase2-7) -> argmax rv/ri (phase9)
// 26624..34816   k (phase3-4) -> xi (phase6-7)
#define XP      160
#define OFF_X   0
#define OFF_Q   0
#define OFF_V   0
#define OFF_AL  8192
#define OFF_QV  8192
#define OFF_E   10240
#define OFF_H1  10240
#define OFF_S   18432
#define OFF_RV  18432
#define OFF_RI  18944
#define OFF_K   26624
#define OFF_XI  26624
#define SMEM_FLOATS 34816    // 139,264 bytes (gfx950 LDS = 160 KiB/CU)

__device__ __forceinline__ float lrelu(float x) { return x > 0.f ? x : 0.01f * x; }
__device__ __forceinline__ float fc(const float4& v, int i) {
    return i == 0 ? v.x : (i == 1 ? v.y : (i == 2 ? v.z : v.w));
}

// ---------------------------------------------------------------------------
__global__ void k_zero(float* __restrict__ p) {
    const int i = blockIdx.x * 256 + threadIdx.x;
    if (i < 2560) p[i] = 0.f;
}

// ---------------------------------------------------------------------------
// BN statistics (sum, sumsq) per (agent, feature) over batch axis.
// grid (64, A), 256 threads; 512-row chunks; float atomics into ws.
// ---------------------------------------------------------------------------
__global__ __launch_bounds__(256) void k_stats(const float* __restrict__ obs,
                                               const float* __restrict__ act,
                                               float* __restrict__ gsum,
                                               float* __restrict__ gsq) {
    const int a = blockIdx.y;
    const int b0 = blockIdx.x * (B_ / 64);
    const int tid = threadIdx.x;
    __shared__ float red[256][8];

    {   // obs: 32 float4 cols x 8 row groups
        const int c = tid & 31, rg = tid >> 5;
        const float4* src = (const float4*)(obs + (size_t)a * B_ * OBS_);
        float4 s = make_float4(0.f,0.f,0.f,0.f), q = make_float4(0.f,0.f,0.f,0.f);
        for (int b = b0 + rg; b < b0 + 512; b += 8) {
            float4 v = src[(size_t)b * 32 + c];
            s.x += v.x; s.y += v.y; s.z += v.z; s.w += v.w;
            q.x += v.x*v.x; q.y += v.y*v.y; q.z += v.z*v.z; q.w += v.w*v.w;
        }
        red[tid][0]=s.x; red[tid][1]=s.y; red[tid][2]=s.z; red[tid][3]=s.w;
        red[tid][4]=q.x; red[tid][5]=q.y; red[tid][6]=q.z; red[tid][7]=q.w;
    }
    __syncthreads();
    if (tid < 128) {
        const int c4 = tid >> 2, j = tid & 3;
        float s = 0.f, q = 0.f;
        #pragma unroll
        for (int rg = 0; rg < 8; rg++) { s += red[rg*32 + c4][j]; q += red[rg*32 + c4][4 + j]; }
        atomicAdd(&gsum[a * F_ + tid], s);
        atomicAdd(&gsq [a * F_ + tid], q);
    }
    __syncthreads();

    {   // act: 8 float4 cols x 32 row groups
        const int c = tid & 7, rg = tid >> 3;
        const float4* src = (const float4*)(act + (size_t)a * B_ * ACT_);
        float4 s = make_float4(0.f,0.f,0.f,0.f), q = make_float4(0.f,0.f,0.f,0.f);
        for (int b = b0 + rg; b < b0 + 512; b += 32) {
            float4 v = src[(size_t)b * 8 + c];
            s.x += v.x; s.y += v.y; s.z += v.z; s.w += v.w;
            q.x += v.x*v.x; q.y += v.y*v.y; q.z += v.z*v.z; q.w += v.w*v.w;
        }
        red[tid][0]=s.x; red[tid][1]=s.y; red[tid][2]=s.z; red[tid][3]=s.w;
        red[tid][4]=q.x; red[tid][5]=q.y; red[tid][6]=q.z; red[tid][7]=q.w;
    }
    __syncthreads();
    if (tid < 32) {
        const int c4 = tid >> 2, j = tid & 3;
        float s = 0.f, q = 0.f;
        #pragma unroll
        for (int rg = 0; rg < 32; rg++) { s += red[rg*8 + c4][j]; q += red[rg*8 + c4][4 + j]; }
        atomicAdd(&gsum[a * F_ + 128 + tid], s);
        atomicAdd(&gsq [a * F_ + 128 + tid], q);
    }
}

__global__ void k_finalize(const float* __restrict__ gsum, const float* __restrict__ gsq,
                           float* __restrict__ mean, float* __restrict__ rstd) {
    const int i = blockIdx.x * 256 + threadIdx.x;
    if (i < A_ * F_) {
        const float m = gsum[i] * (1.0f / B_);
        const float v = gsq[i] * (1.0f / B_) - m * m;  // biased var (torch BN fwd)
        mean[i] = m;
        rstd[i] = rsqrtf(v + 1e-5f);
    }
}

// ---------------------------------------------------------------------------
// Fold BN (normalize + affine) into the weights:
//   W2[a][f][c] = rstd[a,f] * gamma[a,f] * W[a][f][c]
//   b2[a][c]    = bias[a,c] + sum_f (beta[a,f] - mean*rstd*gamma) * W[a][f][c]
// obs stats are the first 128 of the 160-stride stats arrays (same data for
// the s-branch), so rstd/mean always indexed with stride F_.
// ---------------------------------------------------------------------------
__global__ void k_fold_scale(const float* __restrict__ W, const float* __restrict__ gamma,
                             const float* __restrict__ rstd, float* __restrict__ W2,
                             int F) {
    const int i = blockIdx.x * 256 + threadIdx.x;
    const int total = A_ * F * E_;
    if (i < total) {
        const int a = i / (F * E_);
        const int f = (i / E_) % F;
        W2[i] = W[i] * gamma[a * F + f] * rstd[a * F_ + f];
    }
}

__global__ void k_fold_bias(const float* __restrict__ W, const float* __restrict__ gamma,
                            const float* __restrict__ beta, const float* __restrict__ bias,
                            const float* __restrict__ mean, const float* __restrict__ rstd,
                            float* __restrict__ b2, int F) {
    const int a = blockIdx.x;
    const int c = threadIdx.x;   // 128 threads
    float acc = bias[a * E_ + c];
    for (int f = 0; f < F; f++) {
        const float coef = beta[a * F + f] - mean[a * F_ + f] * rstd[a * F_ + f] * gamma[a * F + f];
        acc += coef * W[((size_t)a * F + f) * E_ + c];
    }
    b2[a * E_ + c] = acc;
}

// ---------------------------------------------------------------------------
// Fused main kernel. Block = 512 threads, 8 batch rows x all 8 agents
// (64 GEMM rows). Everything LDS-resident; no global intermediates.
// ---------------------------------------------------------------------------
__global__ __launch_bounds__(512) void k_fused(
    const float* __restrict__ obs, const float* __restrict__ act,
    const float* __restrict__ Wg2, const float* __restrict__ bg2,
    const float* __restrict__ Ws2, const float* __restrict__ bs2,
    const float* __restrict__ Wq, const float* __restrict__ Wk, const float* __restrict__ Wv,
    const float* __restrict__ Wf1, const float* __restrict__ bf1,
    const float* __restrict__ Wf2, const float* __restrict__ bf2,
    float* __restrict__ out) {
    extern __shared__ float sm[];
    const int b0 = blockIdx.x * 8;
    const int tid = threadIdx.x;

    // ---- phase 1: load raw combined [R=a*8+r][160] ----
    for (int i = tid; i < 2048; i += 512) {        // obs: 64 rows x 32 f4
        const int R = i >> 5, c = i & 31;
        const int a = R >> 3, r = R & 7;
        float4 v = *(const float4*)(obs + ((size_t)a * B_ + b0 + r) * OBS_ + c * 4);
        *(float4*)&sm[OFF_X + R * XP + c * 4] = v;
    }
    {                                              // act: 64 rows x 8 f4
        const int R = tid >> 3, c = tid & 7;
        const int a = R >> 3, r = R & 7;
        float4 v = *(const float4*)(act + ((size_t)a * B_ + b0 + r) * ACT_ + c * 4);
        *(float4*)&sm[OFF_X + R * XP + 128 + c * 4] = v;
    }
    __syncthreads();

    const int cg = tid & 31, rg = tid >> 5;
    const int c0 = cg * 4, r0 = rg * 4;
    const int aR = r0 >> 3;                        // agent of this thread's 4 rows

    // ---- phase 2: e = lrelu(x @ Wg2 + bg2) [K=160], s = lrelu(x @ Ws2 + bs2) [K=128] ----
    {
        float4 ae[4], as[4];
        #pragma unroll
        for (int rr = 0; rr < 4; rr++) { ae[rr] = make_float4(0.f,0.f,0.f,0.f); as[rr] = make_float4(0.f,0.f,0.f,0.f); }
        const float* WgA = Wg2 + (size_t)aR * F_ * E_;
        const float* WsA = Ws2 + (size_t)aR * OBS_ * E_;
        for (int f = 0; f < 128; f += 4) {
            float4 xr[4];
            #pragma unroll
            for (int rr = 0; rr < 4; rr++) xr[rr] = *(const float4*)&sm[OFF_X + (r0 + rr) * XP + f];
            #pragma unroll
            for (int ff = 0; ff < 4; ff++) {
                float4 wg = *(const float4*)(WgA + (size_t)(f + ff) * E_ + c0);
                float4 ws = *(const float4*)(WsA + (size_t)(f + ff) * E_ + c0);
                #pragma unroll
                for (int rr = 0; rr < 4; rr++) {
                    const float xv = fc(xr[rr], ff);
                    ae[rr].x += xv*wg.x; ae[rr].y += xv*wg.y; ae[rr].z += xv*wg.z; ae[rr].w += xv*wg.w;
                    as[rr].x += xv*ws.x; as[rr].y += xv*ws.y; as[rr].z += xv*ws.z; as[rr].w += xv*ws.w;
                }
            }
        }
        for (int f = 128; f < 160; f += 4) {       // act tail: e only
            float4 xr[4];
            #pragma unroll
            for (int rr = 0; rr < 4; rr++) xr[rr] = *(const float4*)&sm[OFF_X + (r0 + rr) * XP + f];
            #pragma unroll
            for (int ff = 0; ff < 4; ff++) {
                float4 wg = *(const float4*)(WgA + (size_t)(f + ff) * E_ + c0);
                #pragma unroll
                for (int rr = 0; rr < 4; rr++) {
                    const float xv = fc(xr[rr], ff);
                    ae[rr].x += xv*wg.x; ae[rr].y += xv*wg.y; ae[rr].z += xv*wg.z; ae[rr].w += xv*wg.w;
                }
            }
        }
        const float4 bgv = *(const float4*)(bg2 + aR * E_ + c0);
        const float4 bsv = *(const float4*)(bs2 + aR * E_ + c0);
        #pragma unroll
        for (int rr = 0; rr < 4; rr++) {
            float4 e, s;
            e.x = lrelu(ae[rr].x + bgv.x); e.y = lrelu(ae[rr].y + bgv.y);
            e.z = lrelu(ae[rr].z + bgv.z); e.w = lrelu(ae[rr].w + bgv.w);
            s.x = lrelu(as[rr].x + bsv.x); s.y = lrelu(as[rr].y + bsv.y);
            s.z = lrelu(as[rr].z + bsv.z); s.w = lrelu(as[rr].w + bsv.w);
            *(float4*)&sm[OFF_E + (r0 + rr) * E_ + c0] = e;
            *(float4*)&sm[OFF_S + (r0 + rr) * E_ + c0] = s;
        }
    }
    __syncthreads();   // x dead from here; its head region becomes q

    // ---- phase 3: q = e @ Wq, k = e @ Wk [K=128, cols=(h,d)] ----
    {
        float4 aq[4], ak[4];
        #pragma unroll
        for (int rr = 0; rr < 4; rr++) { aq[rr] = make_float4(0.f,0.f,0.f,0.f); ak[rr] = make_float4(0.f,0.f,0.f,0.f); }
        const int h = c0 >> 5, d0 = c0 & 31;
        const float* WqA = Wq + (size_t)h * E_ * D_ + d0;
        const float* WkA = Wk + (size_t)h * E_ * D_ + d0;
        for (int f = 0; f < 128; f += 4) {
            float4 er[4];
            #pragma unroll
            for (int rr = 0; rr < 4; rr++) er[rr] = *(const float4*)&sm[OFF_E + (r0 + rr) * E_ + f];
            #pragma unroll
            for (int ff = 0; ff < 4; ff++) {
                float4 wq = *(const float4*)(WqA + (size_t)(f + ff) * D_);
                float4 wk = *(const float4*)(WkA + (size_t)(f + ff) * D_);
                #pragma unroll
                for (int rr = 0; rr < 4; rr++) {
                    const float ev = fc(er[rr], ff);
                    aq[rr].x += ev*wq.x; aq[rr].y += ev*wq.y; aq[rr].z += ev*wq.z; aq[rr].w += ev*wq.w;
                    ak[rr].x += ev*wk.x; ak[rr].y += ev*wk.y; ak[rr].z += ev*wk.z; ak[rr].w += ev*wk.w;
                }
            }
        }
        #pragma unroll
        for (int rr = 0; rr < 4; rr++) {
            *(float4*)&sm[OFF_Q + (r0 + rr) * E_ + c0] = aq[rr];
            *(float4*)&sm[OFF_K + (r0 + rr) * E_ + c0] = ak[rr];
        }
    }
    __syncthreads();

    // ---- phase 4: alpha[(h,r)][i][j] = <q_i,k_j>/sqrt(D), diag masked ----
    {
        const int u = tid >> 5, lane = tid & 31;
        #pragma unroll
        for (int rep = 0; rep < 2; rep++) {
            const int pair = u * 2 + rep;          // 32 (h,r) pairs
            const int h = pair >> 3, r = pair & 7;
            #pragma unroll
            for (int p = lane; p < 64; p += 32) {
                const int i = p >> 3, j = p & 7;
                float acc = 0.f;
                #pragma unroll
                for (int d = 0; d < 32; d++)
                    acc += sm[OFF_Q + (i*8 + r) * E_ + h*32 + d] * sm[OFF_K + (j*8 + r) * E_ + h*32 + d];
                sm[OFF_AL + ((h*8 + r) * 8 + i) * 8 + j] = (i == j) ? 0.f : acc * 0.17677669529663687f;
            }
        }
    }
    __syncthreads();   // q dead; its region becomes v

    // ---- phase 5: v = lrelu(e @ Wv) ----
    {
        float4 av[4];
        #pragma unroll
        for (int rr = 0; rr < 4; rr++) av[rr] = make_float4(0.f,0.f,0.f,0.f);
        const int h = c0 >> 5, d0 = c0 & 31;
        const float* WvA = Wv + (size_t)h * E_ * D_ + d0;
        for (int f = 0; f < 128; f += 4) {
            float4 er[4];
            #pragma unroll
            for (int rr = 0; rr < 4; rr++) er[rr] = *(const float4*)&sm[OFF_E + (r0 + rr) * E_ + f];
            #pragma unroll
            for (int ff = 0; ff < 4; ff++) {
                float4 wv = *(const float4*)(WvA + (size_t)(f + ff) * D_);
                #pragma unroll
                for (int rr = 0; rr < 4; rr++) {
                    const float ev = fc(er[rr], ff);
                    av[rr].x += ev*wv.x; av[rr].y += ev*wv.y; av[rr].z += ev*wv.z; av[rr].w += ev*wv.w;
                }
            }
        }
        #pragma unroll
        for (int rr = 0; rr < 4; rr++) {
            float4 v;
            v.x = lrelu(av[rr].x); v.y = lrelu(av[rr].y); v.z = lrelu(av[rr].z); v.w = lrelu(av[rr].w);
            *(float4*)&sm[OFF_V + (r0 + rr) * E_ + c0] = v;
        }
    }
    __syncthreads();   // k dead; its region becomes xi

    // ---- phase 6: xi[R][c] = sum_j alpha[(h,r)][a][j] * v[j*8+r][c] ----
    {
        const int c = tid & 127, rb = tid >> 7;    // 128 cols x 4 row-blocks
        const int h = c >> 5;
        #pragma unroll
        for (int rr = 0; rr < 16; rr++) {
            const int R = rb * 16 + rr;
            const int a = R >> 3, r = R & 7;
            float acc = 0.f;
            #pragma unroll
            for (int j = 0; j < 8; j++)
                acc += sm[OFF_AL + ((h*8 + r) * 8 + a) * 8 + j] * sm[OFF_V + (j*8 + r) * E_ + c];
            sm[OFF_XI + R * E_ + c] = acc;
        }
    }
    __syncthreads();   // e dead; its region becomes h1

    // ---- phase 7: h1 = lrelu([xi, s] @ Wf1 + bf1) [K=256] ----
    {
        float4 acc[4];
        #pragma unroll
        for (int rr = 0; rr < 4; rr++) acc[rr] = make_float4(0.f,0.f,0.f,0.f);
        const float* W1 = Wf1 + (size_t)aR * 2 * E_ * E_;
        for (int f = 0; f < 256; f += 4) {
            float4 xr[4];
            const int base = (f < 128) ? (OFF_XI) : (OFF_S - 128);
            #pragma unroll
            for (int rr = 0; rr < 4; rr++) xr[rr] = *(const float4*)&sm[base + (r0 + rr) * E_ + f];
            #pragma unroll
            for (int ff = 0; ff < 4; ff++) {
                float4 w = *(const float4*)(W1 + (size_t)(f + ff) * E_ + c0);
                #pragma unroll
                for (int rr = 0; rr < 4; rr++) {
                    const float xv = fc(xr[rr], ff);
                    acc[rr].x += xv*w.x; acc[rr].y += xv*w.y; acc[rr].z += xv*w.z; acc[rr].w += xv*w.w;
                }
            }
        }
        const float4 b1 = *(const float4*)(bf1 + aR * E_ + c0);
        #pragma unroll
        for (int rr = 0; rr < 4; rr++) {
            float4 o;
            o.x = lrelu(acc[rr].x + b1.x); o.y = lrelu(acc[rr].y + b1.y);
            o.z = lrelu(acc[rr].z + b1.z); o.w = lrelu(acc[rr].w + b1.w);
            *(float4*)&sm[OFF_H1 + (r0 + rr) * E_ + c0] = o;
        }
    }
    __syncthreads();   // alpha dead; its region becomes qv

    // ---- phase 8: qv = h1 @ Wf2 + bf2 [K=128, N=32] ----
    {
        float a2[4] = {0.f, 0.f, 0.f, 0.f};
        const int c2 = tid & 31, rq = tid >> 5;
        const int r2 = rq * 4, a = r2 >> 3;
        const float* W2 = Wf2 + (size_t)a * E_ * ACT_;
        for (int f = 0; f < 128; f++) {
            const float w = W2[(size_t)f * ACT_ + c2];
            #pragma unroll
            for (int rr = 0; rr < 4; rr++) a2[rr] += sm[OFF_H1 + (r2 + rr) * E_ + f] * w;
        }
        const float b2 = bf2[a * ACT_ + c2];
        #pragma unroll
        for (int rr = 0; rr < 4; rr++) sm[OFF_QV + (r2 + rr) * ACT_ + c2] = a2[rr] + b2;
    }
    __syncthreads();   // s dead; its region becomes argmax scratch

    // ---- phase 9: argmax(action) + gather ----
    {
        const int R = tid >> 3, t = tid & 7;
        const int a = R >> 3, r = R & 7;
        float4 v = *(const float4*)(act + ((size_t)a * B_ + b0 + r) * ACT_ + t * 4);
        float bv = v.x; int bi = t * 4;
        if (v.y > bv) { bv = v.y; bi = t * 4 + 1; }
        if (v.z > bv) { bv = v.z; bi = t * 4 + 2; }
        if (v.w > bv) { bv = v.w; bi = t * 4 + 3; }
        sm[OFF_RV + R * 8 + t] = bv;
        ((int*)sm)[OFF_RI + R * 8 + t] = bi;
    }
    __syncthreads();
    if (tid < 64) {
        const int R = tid;
        const int a = R >> 3, r = R & 7;
        float best = sm[OFF_RV + R * 8]; int besti = ((int*)sm)[OFF_RI + R * 8];
        #pragma unroll
        for (int k = 1; k < 8; k++) {
            const float vk = sm[OFF_RV + R * 8 + k];
            const int   ik = ((int*)sm)[OFF_RI + R * 8 + k];
            if (vk > best || (vk == best && ik < besti)) { best = vk; besti = ik; }
        }
        out[(size_t)a * B_ + b0 + r] = sm[OFF_QV + R * ACT_ + besti];
    }
}

// ---------------------------------------------------------------------------
extern "C" void kernel_launch(void* const* d_in, const int* in_sizes, int n_in,
                              void* d_out, int out_size, void* d_ws, size_t ws_size,
                              hipStream_t stream) {
    const float* obs     = (const float*)d_in[0];
    const float* act     = (const float*)d_in[1];
    const float* g_gamma = (const float*)d_in[2];
    const float* g_beta  = (const float*)d_in[3];
    const float* Wg      = (const float*)d_in[4];
    const float* bg      = (const float*)d_in[5];
    const float* s_gamma = (const float*)d_in[6];
    const float* s_beta  = (const float*)d_in[7];
    const float* Ws      = (const float*)d_in[8];
    const float* bs      = (const float*)d_in[9];
    const float* Wq      = (const float*)d_in[10];
    const float* Wk      = (const float*)d_in[11];
    const float* Wv      = (const float*)d_in[12];
    const float* Wf1     = (const float*)d_in[13];
    const float* bf1     = (const float*)d_in[14];
    const float* Wf2     = (const float*)d_in[15];
    const float* bf2     = (const float*)d_in[16];

    // defensive: if ws is smaller than our (tiny) need, bail out gracefully
    if (ws_size < (size_t)WS_TOTAL * sizeof(float)) return;

    // allow >64KB dynamic LDS (idempotent host call; harmless if unsupported)
    (void)hipFuncSetAttribute((const void*)k_fused,
                              hipFuncAttributeMaxDynamicSharedMemorySize,
                              SMEM_FLOATS * sizeof(float));

    float* ws   = (float*)d_ws;
    float* gsum = ws + WS_GSUM;
    float* gsq  = ws + WS_GSQ;
    float* mean = ws + WS_MEAN;
    float* rstd = ws + WS_RSTD;
    float* Wg2  = ws + WS_WG2;
    float* bg2  = ws + WS_BG2;
    float* Ws2  = ws + WS_WS2;
    float* bs2  = ws + WS_BS2;

    k_zero<<<10, 256, 0, stream>>>(gsum);   // zeroes gsum+gsq (contiguous 2560)
    k_stats<<<dim3(64, A_), 256, 0, stream>>>(obs, act, gsum, gsq);
    k_finalize<<<5, 256, 0, stream>>>(gsum, gsq, mean, rstd);
    k_fold_scale<<<640, 256, 0, stream>>>(Wg, g_gamma, rstd, Wg2, F_);
    k_fold_scale<<<512, 256, 0, stream>>>(Ws, s_gamma, rstd, Ws2, OBS_);
    k_fold_bias<<<A_, 128, 0, stream>>>(Wg, g_gamma, g_beta, bg, mean, rstd, bg2, F_);
    k_fold_bias<<<A_, 128, 0, stream>>>(Ws, s_gamma, s_beta, bs, mean, rstd, bs2, OBS_);
    k_fused<<<B_ / 8, 512, SMEM_FLOATS * sizeof(float), stream>>>(
        obs, act, Wg2, bg2, Ws2, bs2, Wq, Wk, Wv, Wf1, bf1, Wf2, bf2, (float*)d_out);
}

// Round 5
// 1480.649 us; speedup vs baseline: 1.0696x; 1.0696x over previous
//
#include <hip/hip_runtime.h>

#define A_ 8
#define B_ 32768
#define OBS_ 128
#define ACT_ 32
#define F_ 160          // OBS + ACT
#define E_ 128
#define H_ 4
#define D_ 32
#define NB_ 4           // batch rows per block

// ---- workspace layout (floats) — total ~1.21 MB ----
#define WS_GSUM 0
#define WS_GSQ  1280
#define WS_MEAN 2560
#define WS_RSTD 3840
#define WS_WG2  5120                  // 8*160*128 = 163840
#define WS_BG2  (WS_WG2 + 163840)     // 1024
#define WS_WS2  (WS_BG2 + 1024)       // 131072
#define WS_BS2  (WS_WS2 + 131072)     // 1024
#define WS_TOTAL (WS_BS2 + 1024)      // 302080 floats

// ---- fused-kernel LDS layout (floats), phase-overlaid, NB=4 (32 GEMM rows) ----
// 0......4096    q (ph3-4) -> v (ph5-6); X head [32][160] spans 0..5120 (ph1-2)
// 5120...6144    alpha [4][4][8][8] (ph4-6) -> qv [32][32] (ph8-9)
// 6144...10240   e (ph2-5) -> h1 (ph7-8)
// 10240..14336   s (ph2-7) -> argmax rv/ri (ph9)
// 14336..18432   k (ph3-4) -> xi (ph6-7)
#define XP      160
#define OFF_X   0
#define OFF_Q   0
#define OFF_V   0
#define OFF_AL  5120
#define OFF_QV  5120
#define OFF_E   6144
#define OFF_H1  6144
#define OFF_S   10240
#define OFF_RV  10240
#define OFF_RI  10496
#define OFF_K   14336
#define OFF_XI  14336
#define SMEM_FLOATS 18432    // 73,728 B -> 2 blocks/CU (160 KiB LDS)

__device__ __forceinline__ float lrelu(float x) { return x > 0.f ? x : 0.01f * x; }
__device__ __forceinline__ float fc(const float4& v, int i) {
    return i == 0 ? v.x : (i == 1 ? v.y : (i == 2 ? v.z : v.w));
}
// Q/K/V swizzled float index: physical f4-chunk = (c>>2) ^ agent(R).
// Kills phase-4's 4/8-way same-bank row reads (row stride 128 ≡ 0 mod 32 banks;
// the varying axis across lanes is the agent, so XOR it into the bank bits).
__device__ __forceinline__ int qkv_idx(int R, int c) {
    return R * 128 + ((((c >> 2) ^ (R >> 2)) & 31) << 2) + (c & 3);
}

// ---------------------------------------------------------------------------
__global__ void k_zero(float* __restrict__ p) {
    const int i = blockIdx.x * 256 + threadIdx.x;
    if (i < 2560) p[i] = 0.f;
}

// ---------------------------------------------------------------------------
// BN statistics (sum, sumsq) per (agent, feature) over batch axis.
// ---------------------------------------------------------------------------
__global__ __launch_bounds__(256) void k_stats(const float* __restrict__ obs,
                                               const float* __restrict__ act,
                                               float* __restrict__ gsum,
                                               float* __restrict__ gsq) {
    const int a = blockIdx.y;
    const int b0 = blockIdx.x * (B_ / 64);
    const int tid = threadIdx.x;
    __shared__ float red[256][8];

    {   // obs: 32 float4 cols x 8 row groups
        const int c = tid & 31, rg = tid >> 5;
        const float4* src = (const float4*)(obs + (size_t)a * B_ * OBS_);
        float4 s = make_float4(0.f,0.f,0.f,0.f), q = make_float4(0.f,0.f,0.f,0.f);
        for (int b = b0 + rg; b < b0 + 512; b += 8) {
            float4 v = src[(size_t)b * 32 + c];
            s.x += v.x; s.y += v.y; s.z += v.z; s.w += v.w;
            q.x += v.x*v.x; q.y += v.y*v.y; q.z += v.z*v.z; q.w += v.w*v.w;
        }
        red[tid][0]=s.x; red[tid][1]=s.y; red[tid][2]=s.z; red[tid][3]=s.w;
        red[tid][4]=q.x; red[tid][5]=q.y; red[tid][6]=q.z; red[tid][7]=q.w;
    }
    __syncthreads();
    if (tid < 128) {
        const int c4 = tid >> 2, j = tid & 3;
        float s = 0.f, q = 0.f;
        #pragma unroll
        for (int rg = 0; rg < 8; rg++) { s += red[rg*32 + c4][j]; q += red[rg*32 + c4][4 + j]; }
        atomicAdd(&gsum[a * F_ + tid], s);
        atomicAdd(&gsq [a * F_ + tid], q);
    }
    __syncthreads();

    {   // act: 8 float4 cols x 32 row groups
        const int c = tid & 7, rg = tid >> 3;
        const float4* src = (const float4*)(act + (size_t)a * B_ * ACT_);
        float4 s = make_float4(0.f,0.f,0.f,0.f), q = make_float4(0.f,0.f,0.f,0.f);
        for (int b = b0 + rg; b < b0 + 512; b += 32) {
            float4 v = src[(size_t)b * 8 + c];
            s.x += v.x; s.y += v.y; s.z += v.z; s.w += v.w;
            q.x += v.x*v.x; q.y += v.y*v.y; q.z += v.z*v.z; q.w += v.w*v.w;
        }
        red[tid][0]=s.x; red[tid][1]=s.y; red[tid][2]=s.z; red[tid][3]=s.w;
        red[tid][4]=q.x; red[tid][5]=q.y; red[tid][6]=q.z; red[tid][7]=q.w;
    }
    __syncthreads();
    if (tid < 32) {
        const int c4 = tid >> 2, j = tid & 3;
        float s = 0.f, q = 0.f;
        #pragma unroll
        for (int rg = 0; rg < 32; rg++) { s += red[rg*8 + c4][j]; q += red[rg*8 + c4][4 + j]; }
        atomicAdd(&gsum[a * F_ + 128 + tid], s);
        atomicAdd(&gsq [a * F_ + 128 + tid], q);
    }
}

__global__ void k_finalize(const float* __restrict__ gsum, const float* __restrict__ gsq,
                           float* __restrict__ mean, float* __restrict__ rstd) {
    const int i = blockIdx.x * 256 + threadIdx.x;
    if (i < A_ * F_) {
        const float m = gsum[i] * (1.0f / B_);
        const float v = gsq[i] * (1.0f / B_) - m * m;  // biased var (torch BN fwd)
        mean[i] = m;
        rstd[i] = rsqrtf(v + 1e-5f);
    }
}

// ---------------------------------------------------------------------------
// Fold BN (normalize + affine) into weights/biases (see round-1 notes).
// ---------------------------------------------------------------------------
__global__ void k_fold_scale(const float* __restrict__ W, const float* __restrict__ gamma,
                             const float* __restrict__ rstd, float* __restrict__ W2,
                             int F) {
    const int i = blockIdx.x * 256 + threadIdx.x;
    const int total = A_ * F * E_;
    if (i < total) {
        const int a = i / (F * E_);
        const int f = (i / E_) % F;
        W2[i] = W[i] * gamma[a * F + f] * rstd[a * F_ + f];
    }
}

__global__ void k_fold_bias(const float* __restrict__ W, const float* __restrict__ gamma,
                            const float* __restrict__ beta, const float* __restrict__ bias,
                            const float* __restrict__ mean, const float* __restrict__ rstd,
                            float* __restrict__ b2, int F) {
    const int a = blockIdx.x;
    const int c = threadIdx.x;   // 128 threads
    float acc = bias[a * E_ + c];
    for (int f = 0; f < F; f++) {
        const float coef = beta[a * F + f] - mean[a * F_ + f] * rstd[a * F_ + f] * gamma[a * F + f];
        acc += coef * W[((size_t)a * F + f) * E_ + c];
    }
    b2[a * E_ + c] = acc;
}

// ---------------------------------------------------------------------------
// Fused main kernel. 256 threads, NB=4 batch rows x 8 agents (32 GEMM rows).
// 73.7 KB LDS -> 2 blocks/CU for barrier-stall overlap.
// ---------------------------------------------------------------------------
__global__ __launch_bounds__(256, 2) void k_fused(
    const float* __restrict__ obs, const float* __restrict__ act,
    const float* __restrict__ Wg2, const float* __restrict__ bg2,
    const float* __restrict__ Ws2, const float* __restrict__ bs2,
    const float* __restrict__ Wq, const float* __restrict__ Wk, const float* __restrict__ Wv,
    const float* __restrict__ Wf1, const float* __restrict__ bf1,
    const float* __restrict__ Wf2, const float* __restrict__ bf2,
    float* __restrict__ out) {
    extern __shared__ float sm[];
    const int b0 = blockIdx.x * NB_;
    const int tid = threadIdx.x;

    // ---- phase 1: load raw combined [R=a*4+r][160] ----
    for (int i = tid; i < 1024; i += 256) {        // obs: 32 rows x 32 f4
        const int R = i >> 5, c = i & 31;
        const int a = R >> 2, r = R & 3;
        float4 v = *(const float4*)(obs + ((size_t)a * B_ + b0 + r) * OBS_ + c * 4);
        *(float4*)&sm[OFF_X + R * XP + c * 4] = v;
    }
    {                                              // act: 32 rows x 8 f4
        const int R = tid >> 3, c = tid & 7;
        const int a = R >> 2, r = R & 3;
        float4 v = *(const float4*)(act + ((size_t)a * B_ + b0 + r) * ACT_ + c * 4);
        *(float4*)&sm[OFF_X + R * XP + 128 + c * 4] = v;
    }
    __syncthreads();

    const int cg = tid & 31, rg = tid >> 5;        // rg in 0..7
    const int c0 = cg * 4, r0 = rg * 4;
    const int aR = rg;                             // agent of this thread's 4 rows

    // ---- phase 2: e = lrelu(x @ Wg2 + bg2) [K=160], s = lrelu(x @ Ws2 + bs2) [K=128] ----
    {
        float4 ae[4], as[4];
        #pragma unroll
        for (int rr = 0; rr < 4; rr++) { ae[rr] = make_float4(0.f,0.f,0.f,0.f); as[rr] = make_float4(0.f,0.f,0.f,0.f); }
        const float* WgA = Wg2 + (size_t)aR * F_ * E_;
        const float* WsA = Ws2 + (size_t)aR * OBS_ * E_;
        #pragma unroll 2
        for (int f = 0; f < 128; f += 4) {
            float4 xr[4];
            #pragma unroll
            for (int rr = 0; rr < 4; rr++) xr[rr] = *(const float4*)&sm[OFF_X + (r0 + rr) * XP + f];
            #pragma unroll
            for (int ff = 0; ff < 4; ff++) {
                float4 wg = *(const float4*)(WgA + (size_t)(f + ff) * E_ + c0);
                float4 ws = *(const float4*)(WsA + (size_t)(f + ff) * E_ + c0);
                #pragma unroll
                for (int rr = 0; rr < 4; rr++) {
                    const float xv = fc(xr[rr], ff);
                    ae[rr].x += xv*wg.x; ae[rr].y += xv*wg.y; ae[rr].z += xv*wg.z; ae[rr].w += xv*wg.w;
                    as[rr].x += xv*ws.x; as[rr].y += xv*ws.y; as[rr].z += xv*ws.z; as[rr].w += xv*ws.w;
                }
            }
        }
        #pragma unroll 2
        for (int f = 128; f < 160; f += 4) {       // act tail: e only
            float4 xr[4];
            #pragma unroll
            for (int rr = 0; rr < 4; rr++) xr[rr] = *(const float4*)&sm[OFF_X + (r0 + rr) * XP + f];
            #pragma unroll
            for (int ff = 0; ff < 4; ff++) {
                float4 wg = *(const float4*)(WgA + (size_t)(f + ff) * E_ + c0);
                #pragma unroll
                for (int rr = 0; rr < 4; rr++) {
                    const float xv = fc(xr[rr], ff);
                    ae[rr].x += xv*wg.x; ae[rr].y += xv*wg.y; ae[rr].z += xv*wg.z; ae[rr].w += xv*wg.w;
                }
            }
        }
        const float4 bgv = *(const float4*)(bg2 + aR * E_ + c0);
        const float4 bsv = *(const float4*)(bs2 + aR * E_ + c0);
        #pragma unroll
        for (int rr = 0; rr < 4; rr++) {
            float4 e, s;
            e.x = lrelu(ae[rr].x + bgv.x); e.y = lrelu(ae[rr].y + bgv.y);
            e.z = lrelu(ae[rr].z + bgv.z); e.w = lrelu(ae[rr].w + bgv.w);
            s.x = lrelu(as[rr].x + bsv.x); s.y = lrelu(as[rr].y + bsv.y);
            s.z = lrelu(as[rr].z + bsv.z); s.w = lrelu(as[rr].w + bsv.w);
            *(float4*)&sm[OFF_E + (r0 + rr) * E_ + c0] = e;
            *(float4*)&sm[OFF_S + (r0 + rr) * E_ + c0] = s;
        }
    }
    __syncthreads();   // x dead; head region becomes q (swizzled)

    // ---- phase 3: q = e @ Wq, k = e @ Wk [K=128, cols=(h,d)] ----
    {
        float4 aq[4], ak[4];
        #pragma unroll
        for (int rr = 0; rr < 4; rr++) { aq[rr] = make_float4(0.f,0.f,0.f,0.f); ak[rr] = make_float4(0.f,0.f,0.f,0.f); }
        const int h = c0 >> 5, d0 = c0 & 31;
        const float* WqA = Wq + (size_t)h * E_ * D_ + d0;
        const float* WkA = Wk + (size_t)h * E_ * D_ + d0;
        #pragma unroll 2
        for (int f = 0; f < 128; f += 4) {
            float4 er[4];
            #pragma unroll
            for (int rr = 0; rr < 4; rr++) er[rr] = *(const float4*)&sm[OFF_E + (r0 + rr) * E_ + f];
            #pragma unroll
            for (int ff = 0; ff < 4; ff++) {
                float4 wq = *(const float4*)(WqA + (size_t)(f + ff) * D_);
                float4 wk = *(const float4*)(WkA + (size_t)(f + ff) * D_);
                #pragma unroll
                for (int rr = 0; rr < 4; rr++) {
                    const float ev = fc(er[rr], ff);
                    aq[rr].x += ev*wq.x; aq[rr].y += ev*wq.y; aq[rr].z += ev*wq.z; aq[rr].w += ev*wq.w;
                    ak[rr].x += ev*wk.x; ak[rr].y += ev*wk.y; ak[rr].z += ev*wk.z; ak[rr].w += ev*wk.w;
                }
            }
        }
        const int chs = (cg ^ aR) << 2;            // swizzled chunk base
        #pragma unroll
        for (int rr = 0; rr < 4; rr++) {
            *(float4*)&sm[OFF_Q + (r0 + rr) * E_ + chs] = aq[rr];
            *(float4*)&sm[OFF_K + (r0 + rr) * E_ + chs] = ak[rr];
        }
    }
    __syncthreads();

    // ---- phase 4: alpha[(h,r)][i][j] = <q_i,k_j>/sqrt(D), diag masked ----
    {
        const int u = tid >> 5, lane = tid & 31;
        #pragma unroll
        for (int rep = 0; rep < 2; rep++) {
            const int pair = u * 2 + rep;          // 16 (h,r) pairs
            const int h = pair >> 2, r = pair & 3;
            #pragma unroll
            for (int p = lane; p < 64; p += 32) {
                const int i = p >> 3, j = p & 7;
                float acc = 0.f;
                #pragma unroll
                for (int d = 0; d < 32; d++)
                    acc += sm[OFF_Q + qkv_idx(i * 4 + r, h * 32 + d)]
                         * sm[OFF_K + qkv_idx(j * 4 + r, h * 32 + d)];
                sm[OFF_AL + ((h * 4 + r) * 8 + i) * 8 + j] = (i == j) ? 0.f : acc * 0.17677669529663687f;
            }
        }
    }
    __syncthreads();   // q dead; its region becomes v

    // ---- phase 5: v = lrelu(e @ Wv) ----
    {
        float4 av[4];
        #pragma unroll
        for (int rr = 0; rr < 4; rr++) av[rr] = make_float4(0.f,0.f,0.f,0.f);
        const int h = c0 >> 5, d0 = c0 & 31;
        const float* WvA = Wv + (size_t)h * E_ * D_ + d0;
        #pragma unroll 2
        for (int f = 0; f < 128; f += 4) {
            float4 er[4];
            #pragma unroll
            for (int rr = 0; rr < 4; rr++) er[rr] = *(const float4*)&sm[OFF_E + (r0 + rr) * E_ + f];
            #pragma unroll
            for (int ff = 0; ff < 4; ff++) {
                float4 wv = *(const float4*)(WvA + (size_t)(f + ff) * D_);
                #pragma unroll
                for (int rr = 0; rr < 4; rr++) {
                    const float ev = fc(er[rr], ff);
                    av[rr].x += ev*wv.x; av[rr].y += ev*wv.y; av[rr].z += ev*wv.z; av[rr].w += ev*wv.w;
                }
            }
        }
        const int chs = (cg ^ aR) << 2;
        #pragma unroll
        for (int rr = 0; rr < 4; rr++) {
            float4 v;
            v.x = lrelu(av[rr].x); v.y = lrelu(av[rr].y); v.z = lrelu(av[rr].z); v.w = lrelu(av[rr].w);
            *(float4*)&sm[OFF_V + (r0 + rr) * E_ + chs] = v;
        }
    }
    __syncthreads();   // k dead; its region becomes xi

    // ---- phase 6: xi[R][c] = sum_j alpha[(h,r)][a][j] * v[j*4+r][c] ----
    {
        const int c = tid & 127, rb = tid >> 7;    // 128 cols x 2 row-blocks
        const int h = c >> 5;
        #pragma unroll
        for (int rr = 0; rr < 16; rr++) {
            const int R = rb * 16 + rr;
            const int a = R >> 2, r = R & 3;
            float acc = 0.f;
            #pragma unroll
            for (int j = 0; j < 8; j++)
                acc += sm[OFF_AL + ((h * 4 + r) * 8 + a) * 8 + j]
                     * sm[OFF_V + qkv_idx(j * 4 + r, c)];
            sm[OFF_XI + R * E_ + c] = acc;
        }
    }
    __syncthreads();   // e dead; its region becomes h1

    // ---- phase 7: h1 = lrelu([xi, s] @ Wf1 + bf1) [K=256] ----
    {
        float4 acc[4];
        #pragma unroll
        for (int rr = 0; rr < 4; rr++) acc[rr] = make_float4(0.f,0.f,0.f,0.f);
        const float* W1 = Wf1 + (size_t)aR * 2 * E_ * E_;
        #pragma unroll 2
        for (int f = 0; f < 256; f += 4) {
            float4 xr[4];
            const int base = (f < 128) ? (OFF_XI) : (OFF_S - 128);
            #pragma unroll
            for (int rr = 0; rr < 4; rr++) xr[rr] = *(const float4*)&sm[base + (r0 + rr) * E_ + f];
            #pragma unroll
            for (int ff = 0; ff < 4; ff++) {
                float4 w = *(const float4*)(W1 + (size_t)(f + ff) * E_ + c0);
                #pragma unroll
                for (int rr = 0; rr < 4; rr++) {
                    const float xv = fc(xr[rr], ff);
                    acc[rr].x += xv*w.x; acc[rr].y += xv*w.y; acc[rr].z += xv*w.z; acc[rr].w += xv*w.w;
                }
            }
        }
        const float4 b1 = *(const float4*)(bf1 + aR * E_ + c0);
        #pragma unroll
        for (int rr = 0; rr < 4; rr++) {
            float4 o;
            o.x = lrelu(acc[rr].x + b1.x); o.y = lrelu(acc[rr].y + b1.y);
            o.z = lrelu(acc[rr].z + b1.z); o.w = lrelu(acc[rr].w + b1.w);
            *(float4*)&sm[OFF_H1 + (r0 + rr) * E_ + c0] = o;
        }
    }
    __syncthreads();   // alpha dead; its region becomes qv

    // ---- phase 8: qv = h1 @ Wf2 + bf2 [K=128, N=32] ----
    {
        float a2[4] = {0.f, 0.f, 0.f, 0.f};
        const int c2 = tid & 31, rq = tid >> 5;
        const int r2 = rq * 4, a = rq;
        const float* W2 = Wf2 + (size_t)a * E_ * ACT_;
        #pragma unroll 4
        for (int f = 0; f < 128; f++) {
            const float w = W2[(size_t)f * ACT_ + c2];
            #pragma unroll
            for (int rr = 0; rr < 4; rr++) a2[rr] += sm[OFF_H1 + (r2 + rr) * E_ + f] * w;
        }
        const float b2 = bf2[a * ACT_ + c2];
        #pragma unroll
        for (int rr = 0; rr < 4; rr++) sm[OFF_QV + (r2 + rr) * ACT_ + c2] = a2[rr] + b2;
    }
    __syncthreads();   // s dead; its region becomes argmax scratch

    // ---- phase 9: argmax(action) + gather ----
    {
        const int R = tid >> 3, t = tid & 7;
        const int a = R >> 2, r = R & 3;
        float4 v = *(const float4*)(act + ((size_t)a * B_ + b0 + r) * ACT_ + t * 4);
        float bv = v.x; int bi = t * 4;
        if (v.y > bv) { bv = v.y; bi = t * 4 + 1; }
        if (v.z > bv) { bv = v.z; bi = t * 4 + 2; }
        if (v.w > bv) { bv = v.w; bi = t * 4 + 3; }
        sm[OFF_RV + R * 8 + t] = bv;
        ((int*)sm)[OFF_RI + R * 8 + t] = bi;
    }
    __syncthreads();
    if (tid < 32) {
        const int R = tid;
        const int a = R >> 2, r = R & 3;
        float best = sm[OFF_RV + R * 8]; int besti = ((int*)sm)[OFF_RI + R * 8];
        #pragma unroll
        for (int k = 1; k < 8; k++) {
            const float vk = sm[OFF_RV + R * 8 + k];
            const int   ik = ((int*)sm)[OFF_RI + R * 8 + k];
            if (vk > best || (vk == best && ik < besti)) { best = vk; besti = ik; }
        }
        out[(size_t)a * B_ + b0 + r] = sm[OFF_QV + R * ACT_ + besti];
    }
}

// ---------------------------------------------------------------------------
extern "C" void kernel_launch(void* const* d_in, const int* in_sizes, int n_in,
                              void* d_out, int out_size, void* d_ws, size_t ws_size,
                              hipStream_t stream) {
    const float* obs     = (const float*)d_in[0];
    const float* act     = (const float*)d_in[1];
    const float* g_gamma = (const float*)d_in[2];
    const float* g_beta  = (const float*)d_in[3];
    const float* Wg      = (const float*)d_in[4];
    const float* bg      = (const float*)d_in[5];
    const float* s_gamma = (const float*)d_in[6];
    const float* s_beta  = (const float*)d_in[7];
    const float* Ws      = (const float*)d_in[8];
    const float* bs      = (const float*)d_in[9];
    const float* Wq      = (const float*)d_in[10];
    const float* Wk      = (const float*)d_in[11];
    const float* Wv      = (const float*)d_in[12];
    const float* Wf1     = (const float*)d_in[13];
    const float* bf1     = (const float*)d_in[14];
    const float* Wf2     = (const float*)d_in[15];
    const float* bf2     = (const float*)d_in[16];

    if (ws_size < (size_t)WS_TOTAL * sizeof(float)) return;

    (void)hipFuncSetAttribute((const void*)k_fused,
                              hipFuncAttributeMaxDynamicSharedMemorySize,
                              SMEM_FLOATS * sizeof(float));

    float* ws   = (float*)d_ws;
    float* gsum = ws + WS_GSUM;
    float* gsq  = ws + WS_GSQ;
    float* mean = ws + WS_MEAN;
    float* rstd = ws + WS_RSTD;
    float* Wg2  = ws + WS_WG2;
    float* bg2  = ws + WS_BG2;
    float* Ws2  = ws + WS_WS2;
    float* bs2  = ws + WS_BS2;

    k_zero<<<10, 256, 0, stream>>>(gsum);
    k_stats<<<dim3(64, A_), 256, 0, stream>>>(obs, act, gsum, gsq);
    k_finalize<<<5, 256, 0, stream>>>(gsum, gsq, mean, rstd);
    k_fold_scale<<<640, 256, 0, stream>>>(Wg, g_gamma, rstd, Wg2, F_);
    k_fold_scale<<<512, 256, 0, stream>>>(Ws, s_gamma, rstd, Ws2, OBS_);
    k_fold_bias<<<A_, 128, 0, stream>>>(Wg, g_gamma, g_beta, bg, mean, rstd, bg2, F_);
    k_fold_bias<<<A_, 128, 0, stream>>>(Ws, s_gamma, s_beta, bs, mean, rstd, bs2, OBS_);
    k_fused<<<B_ / NB_, 256, SMEM_FLOATS * sizeof(float), stream>>>(
        obs, act, Wg2, bg2, Ws2, bs2, Wq, Wk, Wv, Wf1, bf1, Wf2, bf2, (float*)d_out);
}

// Round 6
// 1048.463 us; speedup vs baseline: 1.5105x; 1.4122x over previous
//
#include <hip/hip_runtime.h>

#define A_ 8
#define B_ 32768
#define OBS_ 128
#define ACT_ 32
#define F_ 160
#define E_ 128
#define H_ 4
#define D_ 32
#define NB_ 16          // batch rows per block -> 128 GEMM rows (8 agents x 16)

typedef __attribute__((ext_vector_type(8))) short s16x8;   // 8 bf16
typedef __attribute__((ext_vector_type(4))) float f32x4;   // MFMA acc

__device__ __forceinline__ float bf2f(ushort u) {
    union { uint i; float f; } v; v.i = ((uint)u) << 16; return v.f;
}
__device__ __forceinline__ ushort f2bf(float x) {   // RNE
    union { float f; uint i; } v; v.f = x;
    return (ushort)((v.i + 0x7FFF + ((v.i >> 16) & 1)) >> 16);
}
__device__ __forceinline__ float lrelu(float x) { return x > 0.f ? x : 0.01f * x; }

#define MFMA16(a, b, c) __builtin_amdgcn_mfma_f32_16x16x32_bf16((a), (b), (c), 0, 0, 0)

// ---- workspace byte offsets ----
#define WSB_GSUM   0          // f32[1280]
#define WSB_GSQ    5120
#define WSB_MEAN   10240
#define WSB_RSTD   15360
#define WSB_BG2    20480      // f32[8*128]
#define WSB_BS2    24576
#define WSB_WGT    28672      // bf16 [8][128][160]
#define WSB_WSTH   356352     // bf16 [8][128][128]
#define WSB_WSTL   618496
#define WSB_WQT    880640     // bf16 [4][32][128]
#define WSB_WKT    913408
#define WSB_WVT    946176
#define WSB_WF1T   978944     // bf16 [8][128][256]
#define WSB_WF1TL  1503232    // bf16 [8][128][128] (lo of s-half)
#define WSB_WF2T   1765376    // f32  [8][32][128]
#define WSB_TOTAL  1896448

// ---- k_fused LDS byte layout (163840 = 160 KiB exactly) ----
// X slots (0..77824): slot m = 9728 B: x_hi[16][168] (5376) + x_lo[16][136] (4352)
//   after phase 2b slot m holds s_hi[16][136] (+0) and s_lo[16][136] (+4352)
#define SLOT(m)     ((m) * 9728)
#define XHI(m,r,c)  (SLOT(m) + (r) * 336 + (c) * 2)
#define XLO(m,r,c)  (SLOT(m) + 5376 + (r) * 272 + (c) * 2)
#define SHI(m,r,c)  (SLOT(m) + (r) * 272 + (c) * 2)
#define SLO(m,r,c)  (SLOT(m) + 4352 + (r) * 272 + (c) * 2)
#define OFF_E   77824                          // e_hi [128][136]; later xi_stage [16][136]
#define EA(R,c) (OFF_E + (R) * 272 + (c) * 2)
#define OFF_V   112640                         // v [128][128]
#define VA(R,c) (OFF_V + (R) * 256 + (c) * 2)
#define OFF_QH  145920                         // q16 [128][16] bf16, XOR-swizzled
#define OFF_KH  150272
#define OFF_AL  154624                         // alpha bf16 [4][16][8][8]
#define OFF_BI  162816                         // int[128]
#define OFF_PART 163328                        // f32[16][8]
#define SMEM_BYTES 163840
// swizzle: XOR the agent (R>>4, 3 bits) into byte-addr bits 4..6 so rows 16 apart
// (same r, different agent) land on different banks for the alpha dot reads.
__device__ __forceinline__ int qswz(int R, int cb) {
    int a = R * 32 + cb; return a ^ (((R >> 4) & 7) << 4);
}

// ---------------------------------------------------------------------------
__global__ void k_zero(float* __restrict__ p) {
    const int i = blockIdx.x * 256 + threadIdx.x;
    if (i < 2560) p[i] = 0.f;
}

// ---------------------------------------------------------------------------
__global__ __launch_bounds__(256) void k_stats(const float* __restrict__ obs,
                                               const float* __restrict__ act,
                                               float* __restrict__ gsum,
                                               float* __restrict__ gsq) {
    const int a = blockIdx.y;
    const int b0 = blockIdx.x * (B_ / 64);
    const int tid = threadIdx.x;
    __shared__ float red[256][8];

    {
        const int c = tid & 31, rg = tid >> 5;
        const float4* src = (const float4*)(obs + (size_t)a * B_ * OBS_);
        float4 s = make_float4(0.f,0.f,0.f,0.f), q = make_float4(0.f,0.f,0.f,0.f);
        for (int b = b0 + rg; b < b0 + 512; b += 8) {
            float4 v = src[(size_t)b * 32 + c];
            s.x += v.x; s.y += v.y; s.z += v.z; s.w += v.w;
            q.x += v.x*v.x; q.y += v.y*v.y; q.z += v.z*v.z; q.w += v.w*v.w;
        }
        red[tid][0]=s.x; red[tid][1]=s.y; red[tid][2]=s.z; red[tid][3]=s.w;
        red[tid][4]=q.x; red[tid][5]=q.y; red[tid][6]=q.z; red[tid][7]=q.w;
    }
    __syncthreads();
    if (tid < 128) {
        const int c4 = tid >> 2, j = tid & 3;
        float s = 0.f, q = 0.f;
        #pragma unroll
        for (int rg = 0; rg < 8; rg++) { s += red[rg*32 + c4][j]; q += red[rg*32 + c4][4 + j]; }
        atomicAdd(&gsum[a * F_ + tid], s);
        atomicAdd(&gsq [a * F_ + tid], q);
    }
    __syncthreads();
    {
        const int c = tid & 7, rg = tid >> 3;
        const float4* src = (const float4*)(act + (size_t)a * B_ * ACT_);
        float4 s = make_float4(0.f,0.f,0.f,0.f), q = make_float4(0.f,0.f,0.f,0.f);
        for (int b = b0 + rg; b < b0 + 512; b += 32) {
            float4 v = src[(size_t)b * 8 + c];
            s.x += v.x; s.y += v.y; s.z += v.z; s.w += v.w;
            q.x += v.x*v.x; q.y += v.y*v.y; q.z += v.z*v.z; q.w += v.w*v.w;
        }
        red[tid][0]=s.x; red[tid][1]=s.y; red[tid][2]=s.z; red[tid][3]=s.w;
        red[tid][4]=q.x; red[tid][5]=q.y; red[tid][6]=q.z; red[tid][7]=q.w;
    }
    __syncthreads();
    if (tid < 32) {
        const int c4 = tid >> 2, j = tid & 3;
        float s = 0.f, q = 0.f;
        #pragma unroll
        for (int rg = 0; rg < 32; rg++) { s += red[rg*8 + c4][j]; q += red[rg*8 + c4][4 + j]; }
        atomicAdd(&gsum[a * F_ + 128 + tid], s);
        atomicAdd(&gsq [a * F_ + 128 + tid], q);
    }
}

__global__ void k_finalize(const float* __restrict__ gsum, const float* __restrict__ gsq,
                           float* __restrict__ mean, float* __restrict__ rstd) {
    const int i = blockIdx.x * 256 + threadIdx.x;
    if (i < A_ * F_) {
        const float m = gsum[i] * (1.0f / B_);
        const float v = gsq[i] * (1.0f / B_) - m * m;
        mean[i] = m;
        rstd[i] = rsqrtf(v + 1e-5f);
    }
}

__global__ void k_fold_bias(const float* __restrict__ W, const float* __restrict__ gamma,
                            const float* __restrict__ beta, const float* __restrict__ bias,
                            const float* __restrict__ mean, const float* __restrict__ rstd,
                            float* __restrict__ b2, int F) {
    const int a = blockIdx.x;
    const int c = threadIdx.x;
    float acc = bias[a * E_ + c];
    for (int f = 0; f < F; f++) {
        const float coef = beta[a * F + f] - mean[a * F_ + f] * rstd[a * F_ + f] * gamma[a * F + f];
        acc += coef * W[((size_t)a * F + f) * E_ + c];
    }
    b2[a * E_ + c] = acc;
}

// ---- weight prep: fold + transpose + bf16 (hi/lo where needed) ----
__global__ void k_prep_wgT(const float* __restrict__ Wg, const float* __restrict__ gg,
                           const float* __restrict__ rstd, ushort* __restrict__ WgT) {
    int i = blockIdx.x * 256 + threadIdx.x;      // i = (a*128 + n)*160 + k
    if (i >= 8 * 128 * 160) return;
    int a = i / (128 * 160), rest = i % (128 * 160);
    int n = rest / 160, k = rest % 160;
    float w = Wg[((size_t)a * 160 + k) * 128 + n] * gg[a * 160 + k] * rstd[a * 160 + k];
    WgT[i] = f2bf(w);
}
__global__ void k_prep_wsT(const float* __restrict__ Ws, const float* __restrict__ sg,
                           const float* __restrict__ rstd,
                           ushort* __restrict__ Th, ushort* __restrict__ Tl) {
    int i = blockIdx.x * 256 + threadIdx.x;      // i = (a*128 + n)*128 + k
    if (i >= 8 * 128 * 128) return;
    int a = i / (128 * 128), rest = i % (128 * 128);
    int n = rest / 128, k = rest % 128;
    float w = Ws[((size_t)a * 128 + k) * 128 + n] * sg[a * 128 + k] * rstd[a * 160 + k];
    ushort h = f2bf(w);
    Th[i] = h;
    Tl[i] = f2bf(w - bf2f(h));
}
__global__ void k_prep_qkvT(const float* __restrict__ Wq, const float* __restrict__ Wk,
                            const float* __restrict__ Wv, ushort* __restrict__ Tq,
                            ushort* __restrict__ Tk, ushort* __restrict__ Tv) {
    int i = blockIdx.x * 256 + threadIdx.x;      // i = (h*32 + d)*128 + e
    if (i >= 4 * 32 * 128) return;
    int h = i / (32 * 128), rest = i % (32 * 128);
    int d = rest / 128, e = rest % 128;
    size_t src = ((size_t)h * 128 + e) * 32 + d;
    Tq[i] = f2bf(Wq[src]); Tk[i] = f2bf(Wk[src]); Tv[i] = f2bf(Wv[src]);
}
__global__ void k_prep_f1T(const float* __restrict__ Wf1, ushort* __restrict__ Th,
                           ushort* __restrict__ Tl) {
    int i = blockIdx.x * 256 + threadIdx.x;      // i = (a*128 + n)*256 + k
    if (i >= 8 * 128 * 256) return;
    int a = i / (128 * 256), rest = i % (128 * 256);
    int n = rest / 256, k = rest % 256;
    float w = Wf1[((size_t)a * 256 + k) * 128 + n];
    ushort h = f2bf(w);
    Th[i] = h;
    if (k >= 128) Tl[((size_t)(a * 128 + n)) * 128 + (k - 128)] = f2bf(w - bf2f(h));
}
__global__ void k_prep_f2T(const float* __restrict__ Wf2, float* __restrict__ T) {
    int i = blockIdx.x * 256 + threadIdx.x;      // i = (a*32 + c)*128 + k
    if (i >= 8 * 32 * 128) return;
    int a = i / (32 * 128), rest = i % (32 * 128);
    int c = rest / 128, k = rest % 128;
    T[i] = Wf2[((size_t)a * 128 + k) * 32 + c];
}

// ---------------------------------------------------------------------------
// Fused MFMA kernel: 512 threads (8 waves), 16 batch rows x 8 agents = 128 rows.
// ---------------------------------------------------------------------------
__global__ __launch_bounds__(512, 1) void k_fused(
    const float* __restrict__ obs, const float* __restrict__ act,
    const ushort* __restrict__ WgT, const float* __restrict__ bg2,
    const ushort* __restrict__ WsTh, const ushort* __restrict__ WsTl,
    const float* __restrict__ bs2,
    const ushort* __restrict__ WqT, const ushort* __restrict__ WkT,
    const ushort* __restrict__ WvT,
    const ushort* __restrict__ Wf1T, const ushort* __restrict__ Wf1Tl,
    const float* __restrict__ bf1,
    const float* __restrict__ Wf2T, const float* __restrict__ bfc2,
    float* __restrict__ out) {
    extern __shared__ char smc[];
    const int tid = threadIdx.x;
    const int b0 = blockIdx.x * NB_;
    const int lane = tid & 63, wv = tid >> 6;
    const int l16 = lane & 15, l4 = lane >> 4;

    // ---- ph0: argmax(act) per row (fp32, first-index tie-break) ----
    {
        const int R = tid >> 2, q = tid & 3;
        const int a = R >> 4, r = R & 15;
        const float* ap = act + ((size_t)a * B_ + b0 + r) * 32 + q * 8;
        float bv = -1e30f; int bi = 0;
        #pragma unroll
        for (int u = 0; u < 8; u++) { float x = ap[u]; if (x > bv) { bv = x; bi = q * 8 + u; } }
        #pragma unroll
        for (int off = 1; off < 4; off <<= 1) {
            float ov = __shfl_xor(bv, off, 4);
            int   oi = __shfl_xor(bi, off, 4);
            if (ov > bv || (ov == bv && oi < bi)) { bv = ov; bi = oi; }
        }
        if (q == 0) *(int*)(smc + OFF_BI + R * 4) = bi;
    }

    // ---- ph1: load raw inputs -> x_hi (160 cols) / x_lo (obs 128 cols) ----
    for (int i = tid; i < 4096; i += 512) {          // obs: 128 rows x 32 f4
        const int R = i >> 5, c4 = i & 31;
        const int a = R >> 4, r = R & 15;
        float4 v = *(const float4*)(obs + ((size_t)a * B_ + b0 + r) * 128 + c4 * 4);
        float vv[4] = {v.x, v.y, v.z, v.w};
        #pragma unroll
        for (int j = 0; j < 4; j++) {
            ushort h = f2bf(vv[j]);
            *(ushort*)(smc + XHI(a, r, c4 * 4 + j)) = h;
            *(ushort*)(smc + XLO(a, r, c4 * 4 + j)) = f2bf(vv[j] - bf2f(h));
        }
    }
    for (int i = tid; i < 1024; i += 512) {          // act: 128 rows x 8 f4 (hi only)
        const int R = i >> 3, c4 = i & 7;
        const int a = R >> 4, r = R & 15;
        float4 v = *(const float4*)(act + ((size_t)a * B_ + b0 + r) * 32 + c4 * 4);
        float vv[4] = {v.x, v.y, v.z, v.w};
        #pragma unroll
        for (int j = 0; j < 4; j++)
            *(ushort*)(smc + XHI(a, r, 128 + c4 * 4 + j)) = f2bf(vv[j]);
    }
    __syncthreads();

    const int n = wv * 16 + l16;                     // this lane's output column

    // ---- ph2: e = lrelu(x @ WgT + bg2), K=160, 1-pass bf16 ----
    {
        f32x4 acc[8];
        #pragma unroll
        for (int m = 0; m < 8; m++) acc[m] = (f32x4){0.f, 0.f, 0.f, 0.f};
        #pragma unroll
        for (int kc = 0; kc < 5; kc++) {
            const int kof = kc * 32 + l4 * 8;
            #pragma unroll
            for (int m = 0; m < 8; m++) {
                s16x8 a = *(const s16x8*)(smc + XHI(m, l16, kof));
                s16x8 b = *(const s16x8*)(WgT + ((size_t)m * 128 + n) * 160 + kof);
                acc[m] = MFMA16(a, b, acc[m]);
            }
        }
        #pragma unroll
        for (int m = 0; m < 8; m++) {
            const float bb = bg2[m * 128 + n];
            #pragma unroll
            for (int j = 0; j < 4; j++)
                *(ushort*)(smc + EA(m * 16 + l4 * 4 + j, n)) = f2bf(lrelu(acc[m][j] + bb));
        }
    }
    __syncthreads();

    // ---- ph2b: s = lrelu(x @ WsT + bs2), K=128, 3-pass hi/lo; overwrite x slot ----
    for (int m = 0; m < 8; m++) {
        f32x4 acc = (f32x4){0.f, 0.f, 0.f, 0.f};
        #pragma unroll
        for (int kc = 0; kc < 4; kc++) {
            const int kof = kc * 32 + l4 * 8;
            s16x8 ah = *(const s16x8*)(smc + XHI(m, l16, kof));
            s16x8 al = *(const s16x8*)(smc + XLO(m, l16, kof));
            s16x8 bh = *(const s16x8*)(WsTh + ((size_t)m * 128 + n) * 128 + kof);
            s16x8 bl = *(const s16x8*)(WsTl + ((size_t)m * 128 + n) * 128 + kof);
            acc = MFMA16(ah, bh, acc);
            acc = MFMA16(al, bh, acc);
            acc = MFMA16(ah, bl, acc);
        }
        __syncthreads();   // all reads of x slot m done before overwriting it
        const float bb = bs2[m * 128 + n];
        #pragma unroll
        for (int j = 0; j < 4; j++) {
            float s = lrelu(acc[j] + bb);
            ushort h = f2bf(s);
            *(ushort*)(smc + SHI(m, l4 * 4 + j, n)) = h;
            *(ushort*)(smc + SLO(m, l4 * 4 + j, n)) = f2bf(s - bf2f(h));
        }
    }

    // ---- ph3: v = lrelu(e @ WvT), K=128, 1-pass ----
    {
        f32x4 acc[8];
        #pragma unroll
        for (int m = 0; m < 8; m++) acc[m] = (f32x4){0.f, 0.f, 0.f, 0.f};
        const int h = n >> 5, dl = n & 31;
        const ushort* wp = WvT + ((size_t)(h * 32 + dl)) * 128;
        #pragma unroll
        for (int kc = 0; kc < 4; kc++) {
            const int kof = kc * 32 + l4 * 8;
            s16x8 b = *(const s16x8*)(wp + kof);
            #pragma unroll
            for (int m = 0; m < 8; m++) {
                s16x8 a = *(const s16x8*)(smc + EA(m * 16 + l16, kof));
                acc[m] = MFMA16(a, b, acc[m]);
            }
        }
        #pragma unroll
        for (int m = 0; m < 8; m++)
            #pragma unroll
            for (int j = 0; j < 4; j++)
                *(ushort*)(smc + VA(m * 16 + l4 * 4 + j, n)) = f2bf(lrelu(acc[m][j]));
    }

    // ---- ph4: per (head, d-half): q16/k16 MFMA + alpha dots ----
    float da0 = 0.f, da1 = 0.f;
    for (int hh = 0; hh < 8; hh++) {
        const int h = hh >> 1, dh = hh & 1;
        {   // q/k: wave wv owns agent-tile wv, N=16 (this d-half)
            f32x4 aq = (f32x4){0.f, 0.f, 0.f, 0.f}, ak = (f32x4){0.f, 0.f, 0.f, 0.f};
            const int dl = dh * 16 + l16;
            const ushort* wq = WqT + ((size_t)(h * 32 + dl)) * 128;
            const ushort* wk = WkT + ((size_t)(h * 32 + dl)) * 128;
            #pragma unroll
            for (int kc = 0; kc < 4; kc++) {
                const int kof = kc * 32 + l4 * 8;
                s16x8 a  = *(const s16x8*)(smc + EA(wv * 16 + l16, kof));
                s16x8 bq = *(const s16x8*)(wq + kof);
                s16x8 bk = *(const s16x8*)(wk + kof);
                aq = MFMA16(a, bq, aq);
                ak = MFMA16(a, bk, ak);
            }
            __syncthreads();   // previous sub-phase's dot reads finished
            #pragma unroll
            for (int j = 0; j < 4; j++) {
                const int R = wv * 16 + l4 * 4 + j;
                *(ushort*)(smc + OFF_QH + qswz(R, l16 * 2)) = f2bf(aq[j]);
                *(ushort*)(smc + OFF_KH + qswz(R, l16 * 2)) = f2bf(ak[j]);
            }
        }
        __syncthreads();
        #pragma unroll
        for (int p = 0; p < 2; p++) {               // 1024 (r,i,j) dots, 2/thread
            const int e = p * 512 + tid;
            const int j = e & 7, i = (e >> 3) & 7, r = e >> 6;
            const int Rq = i * 16 + r, Rk = j * 16 + r;
            s16x8 q0 = *(const s16x8*)(smc + OFF_QH + qswz(Rq, 0));
            s16x8 q1 = *(const s16x8*)(smc + OFF_QH + qswz(Rq, 16));
            s16x8 k0 = *(const s16x8*)(smc + OFF_KH + qswz(Rk, 0));
            s16x8 k1 = *(const s16x8*)(smc + OFF_KH + qswz(Rk, 16));
            float d = 0.f;
            #pragma unroll
            for (int u = 0; u < 8; u++) d += bf2f((ushort)q0[u]) * bf2f((ushort)k0[u]);
            #pragma unroll
            for (int u = 0; u < 8; u++) d += bf2f((ushort)q1[u]) * bf2f((ushort)k1[u]);
            float& da = p ? da1 : da0;
            if (dh == 0) da = d;
            else {
                const float tot = da + d;
                *(ushort*)(smc + OFF_AL + ((h * 16 + r) * 64 + i * 8 + j) * 2) =
                    (i == j) ? (ushort)0 : f2bf(tot * 0.17677669529663687f);
            }
        }
    }
    __syncthreads();

    // ---- ph5 (per agent m): xi -> f1 -> fused argmax-column dot ----
    for (int m = 0; m < 8; m++) {
        {   // xi_stage[16][136] = sum_j alpha[h][r][m][j] * v[j*16+r][c]
            const int c = tid & 127, rg = tid >> 7;
            const int h = c >> 5;
            #pragma unroll
            for (int rr = 0; rr < 4; rr++) {
                const int r = rg * 4 + rr;
                float acc = 0.f;
                #pragma unroll
                for (int j = 0; j < 8; j++) {
                    const float al = bf2f(*(const ushort*)(smc + OFF_AL + ((h * 16 + r) * 64 + m * 8 + j) * 2));
                    const float vv = bf2f(*(const ushort*)(smc + VA(j * 16 + r, c)));
                    acc += al * vv;
                }
                *(ushort*)(smc + EA(r, c)) = f2bf(acc);
            }
        }
        __syncthreads();
        {   // h1 = lrelu(xi@Wf1[xi-half] + s@Wf1[s-half] + bf1); out-dot at argmax col
            f32x4 acc = (f32x4){0.f, 0.f, 0.f, 0.f};
            const ushort* w1  = Wf1T  + ((size_t)m * 128 + n) * 256;
            const ushort* w1l = Wf1Tl + ((size_t)m * 128 + n) * 128;
            #pragma unroll
            for (int kc = 0; kc < 4; kc++) {
                const int kof = kc * 32 + l4 * 8;
                s16x8 a = *(const s16x8*)(smc + EA(l16, kof));
                s16x8 b = *(const s16x8*)(w1 + kof);
                acc = MFMA16(a, b, acc);
            }
            #pragma unroll
            for (int kc = 0; kc < 4; kc++) {
                const int kof = kc * 32 + l4 * 8;
                s16x8 ah = *(const s16x8*)(smc + SHI(m, l16, kof));
                s16x8 al = *(const s16x8*)(smc + SLO(m, l16, kof));
                s16x8 bh = *(const s16x8*)(w1 + 128 + kof);
                s16x8 bl = *(const s16x8*)(w1l + kof);
                acc = MFMA16(ah, bh, acc);
                acc = MFMA16(al, bh, acc);
                acc = MFMA16(ah, bl, acc);
            }
            const float bb = bf1[m * 128 + n];
            float ps[4];
            #pragma unroll
            for (int j = 0; j < 4; j++) {
                const int r = l4 * 4 + j;
                const int bi = *(const int*)(smc + OFF_BI + (m * 16 + r) * 4);
                const float w2 = Wf2T[((size_t)m * 32 + bi) * 128 + n];
                ps[j] = lrelu(acc[j] + bb) * w2;
            }
            #pragma unroll
            for (int off = 1; off < 16; off <<= 1)
                #pragma unroll
                for (int j = 0; j < 4; j++) ps[j] += __shfl_xor(ps[j], off, 16);
            if (l16 == 0)
                #pragma unroll
                for (int j = 0; j < 4; j++)
                    *(float*)(smc + OFF_PART + ((l4 * 4 + j) * 8 + wv) * 4) = ps[j];
        }
        __syncthreads();
        if (tid < 16) {
            float o = 0.f;
            #pragma unroll
            for (int w = 0; w < 8; w++) o += *(const float*)(smc + OFF_PART + (tid * 8 + w) * 4);
            const int bi = *(const int*)(smc + OFF_BI + (m * 16 + tid) * 4);
            out[(size_t)m * B_ + b0 + tid] = o + bfc2[m * 32 + bi];
        }
        __syncthreads();
    }
}

// ---------------------------------------------------------------------------
extern "C" void kernel_launch(void* const* d_in, const int* in_sizes, int n_in,
                              void* d_out, int out_size, void* d_ws, size_t ws_size,
                              hipStream_t stream) {
    const float* obs     = (const float*)d_in[0];
    const float* act     = (const float*)d_in[1];
    const float* g_gamma = (const float*)d_in[2];
    const float* g_beta  = (const float*)d_in[3];
    const float* Wg      = (const float*)d_in[4];
    const float* bg      = (const float*)d_in[5];
    const float* s_gamma = (const float*)d_in[6];
    const float* s_beta  = (const float*)d_in[7];
    const float* Ws      = (const float*)d_in[8];
    const float* bs      = (const float*)d_in[9];
    const float* Wq      = (const float*)d_in[10];
    const float* Wk      = (const float*)d_in[11];
    const float* Wv      = (const float*)d_in[12];
    const float* Wf1     = (const float*)d_in[13];
    const float* bf1     = (const float*)d_in[14];
    const float* Wf2     = (const float*)d_in[15];
    const float* bf2     = (const float*)d_in[16];

    if (ws_size < (size_t)WSB_TOTAL) return;

    (void)hipFuncSetAttribute((const void*)k_fused,
                              hipFuncAttributeMaxDynamicSharedMemorySize, SMEM_BYTES);

    char* ws = (char*)d_ws;
    float*  gsum  = (float*)(ws + WSB_GSUM);
    float*  gsq   = (float*)(ws + WSB_GSQ);
    float*  mean  = (float*)(ws + WSB_MEAN);
    float*  rstd  = (float*)(ws + WSB_RSTD);
    float*  bg2   = (float*)(ws + WSB_BG2);
    float*  bs2   = (float*)(ws + WSB_BS2);
    ushort* WgT   = (ushort*)(ws + WSB_WGT);
    ushort* WsTh  = (ushort*)(ws + WSB_WSTH);
    ushort* WsTl  = (ushort*)(ws + WSB_WSTL);
    ushort* WqT   = (ushort*)(ws + WSB_WQT);
    ushort* WkT   = (ushort*)(ws + WSB_WKT);
    ushort* WvT   = (ushort*)(ws + WSB_WVT);
    ushort* Wf1T  = (ushort*)(ws + WSB_WF1T);
    ushort* Wf1Tl = (ushort*)(ws + WSB_WF1TL);
    float*  Wf2T  = (float*)(ws + WSB_WF2T);

    k_zero<<<10, 256, 0, stream>>>(gsum);
    k_stats<<<dim3(64, A_), 256, 0, stream>>>(obs, act, gsum, gsq);
    k_finalize<<<5, 256, 0, stream>>>(gsum, gsq, mean, rstd);
    k_fold_bias<<<A_, 128, 0, stream>>>(Wg, g_gamma, g_beta, bg, mean, rstd, bg2, F_);
    k_fold_bias<<<A_, 128, 0, stream>>>(Ws, s_gamma, s_beta, bs, mean, rstd, bs2, OBS_);
    k_prep_wgT<<<640, 256, 0, stream>>>(Wg, g_gamma, rstd, WgT);
    k_prep_wsT<<<512, 256, 0, stream>>>(Ws, s_gamma, rstd, WsTh, WsTl);
    k_prep_qkvT<<<64, 256, 0, stream>>>(Wq, Wk, Wv, WqT, WkT, WvT);
    k_prep_f1T<<<1024, 256, 0, stream>>>(Wf1, Wf1T, Wf1Tl);
    k_prep_f2T<<<128, 256, 0, stream>>>(Wf2, Wf2T);
    k_fused<<<B_ / NB_, 512, SMEM_BYTES, stream>>>(
        obs, act, WgT, bg2, WsTh, WsTl, bs2, WqT, WkT, WvT,
        Wf1T, Wf1Tl, bf1, Wf2T, bf2, (float*)d_out);
}

// Round 7
// 952.951 us; speedup vs baseline: 1.6619x; 1.1002x over previous
//
#include <hip/hip_runtime.h>

#define A_ 8
#define B_ 32768
#define OBS_ 128
#define ACT_ 32
#define F_ 160
#define E_ 128
#define H_ 4
#define D_ 32
#define NB_ 16          // batch rows per block -> 128 GEMM rows (8 agents x 16)

typedef __attribute__((ext_vector_type(8))) short s16x8;   // 8 bf16
typedef __attribute__((ext_vector_type(4))) float f32x4;   // MFMA acc

__device__ __forceinline__ float bf2f(ushort u) {
    union { uint i; float f; } v; v.i = ((uint)u) << 16; return v.f;
}
__device__ __forceinline__ ushort f2bf(float x) {   // RNE
    union { float f; uint i; } v; v.f = x;
    return (ushort)((v.i + 0x7FFF + ((v.i >> 16) & 1)) >> 16);
}
__device__ __forceinline__ float lrelu(float x) { return x > 0.f ? x : 0.01f * x; }

#define MFMA16(a, b, c) __builtin_amdgcn_mfma_f32_16x16x32_bf16((a), (b), (c), 0, 0, 0)

// ---- workspace byte offsets (unchanged from round 6) ----
#define WSB_GSUM   0
#define WSB_GSQ    5120
#define WSB_MEAN   10240
#define WSB_RSTD   15360
#define WSB_BG2    20480
#define WSB_BS2    24576
#define WSB_WGT    28672      // bf16 [8][128][160]
#define WSB_WSTH   356352     // bf16 [8][128][128]
#define WSB_WSTL   618496
#define WSB_WQT    880640     // bf16 [4][32][128]
#define WSB_WKT    913408
#define WSB_WVT    946176
#define WSB_WF1T   978944     // bf16 [8][128][256]
#define WSB_WF1TL  1503232    // bf16 [8][128][128]
#define WSB_WF2T   1765376    // f32  [8][32][128]
#define WSB_TOTAL  1896448

// ---- k_fused LDS byte layout (162304 B) ----
// 0......77824   x slots (hi 336B-rows + lo 272B-rows per agent) ->
//                s compact (0..69632) + alpha (69632..77824) after B2/B3
// 77824..112640  e [128 rows][272B]  -> xi (same macro)
// 112640..145408 v [128][128] bf16, chunk-XOR swizzled
// 145408..161792 q_h / k_h per-head [128 rows][32 d] bf16, chunk-XOR swizzled
// 161792..162304 BI int[128]
#define SLOT(m)     ((m) * 9728)
#define XHI(m,r,c)  (SLOT(m) + (r) * 336 + (c) * 2)
#define XLO(m,r,c)  (SLOT(m) + 5376 + (r) * 272 + (c) * 2)
#define SHI(m,r,c)  ((m) * 8704 + (r) * 272 + (c) * 2)
#define SLO(m,r,c)  ((m) * 8704 + 4352 + (r) * 272 + (c) * 2)
#define AL2(h,r,i,j) (69632 + ((((h) * 16 + (r)) * 8 + (i)) * 8 + (j)) * 2)
#define EA(R,c)     (77824 + (R) * 272 + (c) * 2)
#define OFF_V   112640
#define OFF_QH  145408
#define OFF_KH  153600
#define OFF_BI  161792
#define SMEM_BYTES 162304
// v: row stride 256B == 0 mod 128 -> XOR agent (R>>4) into 16B-chunk index
__device__ __forceinline__ int VA2(int R, int c) {
    return OFF_V + R * 256 + ((((c >> 3) ^ (R >> 4)) & 15) << 4) + ((c & 7) << 1);
}
// q/k per head: row (a*16+r) stride 64B -> XOR agent low bits into chunk (4 chunks)
__device__ __forceinline__ int QHA(int a, int r, int ch) {
    return OFF_QH + ((((a) * 16 + (r)) * 4 + (((ch) ^ (a)) & 3)) << 4);
}
__device__ __forceinline__ int KHA(int a, int r, int ch) {
    return OFF_KH + ((((a) * 16 + (r)) * 4 + (((ch) ^ (a)) & 3)) << 4);
}

// ---------------------------------------------------------------------------
__global__ void k_zero(float* __restrict__ p) {
    const int i = blockIdx.x * 256 + threadIdx.x;
    if (i < 2560) p[i] = 0.f;
}

// ---------------------------------------------------------------------------
__global__ __launch_bounds__(256) void k_stats(const float* __restrict__ obs,
                                               const float* __restrict__ act,
                                               float* __restrict__ gsum,
                                               float* __restrict__ gsq) {
    const int a = blockIdx.y;
    const int b0 = blockIdx.x * 128;             // 256 chunks of 128 rows
    const int tid = threadIdx.x;
    __shared__ float red[256][8];

    {
        const int c = tid & 31, rg = tid >> 5;
        const float4* src = (const float4*)(obs + (size_t)a * B_ * OBS_);
        float4 s = make_float4(0.f,0.f,0.f,0.f), q = make_float4(0.f,0.f,0.f,0.f);
        for (int b = b0 + rg; b < b0 + 128; b += 8) {
            float4 v = src[(size_t)b * 32 + c];
            s.x += v.x; s.y += v.y; s.z += v.z; s.w += v.w;
            q.x += v.x*v.x; q.y += v.y*v.y; q.z += v.z*v.z; q.w += v.w*v.w;
        }
        red[tid][0]=s.x; red[tid][1]=s.y; red[tid][2]=s.z; red[tid][3]=s.w;
        red[tid][4]=q.x; red[tid][5]=q.y; red[tid][6]=q.z; red[tid][7]=q.w;
    }
    __syncthreads();
    if (tid < 128) {
        const int c4 = tid >> 2, j = tid & 3;
        float s = 0.f, q = 0.f;
        #pragma unroll
        for (int rg = 0; rg < 8; rg++) { s += red[rg*32 + c4][j]; q += red[rg*32 + c4][4 + j]; }
        atomicAdd(&gsum[a * F_ + tid], s);
        atomicAdd(&gsq [a * F_ + tid], q);
    }
    __syncthreads();
    {
        const int c = tid & 7, rg = tid >> 3;
        const float4* src = (const float4*)(act + (size_t)a * B_ * ACT_);
        float4 s = make_float4(0.f,0.f,0.f,0.f), q = make_float4(0.f,0.f,0.f,0.f);
        for (int b = b0 + rg; b < b0 + 128; b += 32) {
            float4 v = src[(size_t)b * 8 + c];
            s.x += v.x; s.y += v.y; s.z += v.z; s.w += v.w;
            q.x += v.x*v.x; q.y += v.y*v.y; q.z += v.z*v.z; q.w += v.w*v.w;
        }
        red[tid][0]=s.x; red[tid][1]=s.y; red[tid][2]=s.z; red[tid][3]=s.w;
        red[tid][4]=q.x; red[tid][5]=q.y; red[tid][6]=q.z; red[tid][7]=q.w;
    }
    __syncthreads();
    if (tid < 32) {
        const int c4 = tid >> 2, j = tid & 3;
        float s = 0.f, q = 0.f;
        #pragma unroll
        for (int rg = 0; rg < 32; rg++) { s += red[rg*8 + c4][j]; q += red[rg*8 + c4][4 + j]; }
        atomicAdd(&gsum[a * F_ + 128 + tid], s);
        atomicAdd(&gsq [a * F_ + 128 + tid], q);
    }
}

__global__ void k_finalize(const float* __restrict__ gsum, const float* __restrict__ gsq,
                           float* __restrict__ mean, float* __restrict__ rstd) {
    const int i = blockIdx.x * 256 + threadIdx.x;
    if (i < A_ * F_) {
        const float m = gsum[i] * (1.0f / B_);
        const float v = gsq[i] * (1.0f / B_) - m * m;
        mean[i] = m;
        rstd[i] = rsqrtf(v + 1e-5f);
    }
}

__global__ void k_fold_bias(const float* __restrict__ W, const float* __restrict__ gamma,
                            const float* __restrict__ beta, const float* __restrict__ bias,
                            const float* __restrict__ mean, const float* __restrict__ rstd,
                            float* __restrict__ b2, int F) {
    const int a = blockIdx.x;
    const int c = threadIdx.x;
    float acc = bias[a * E_ + c];
    for (int f = 0; f < F; f++) {
        const float coef = beta[a * F + f] - mean[a * F_ + f] * rstd[a * F_ + f] * gamma[a * F + f];
        acc += coef * W[((size_t)a * F + f) * E_ + c];
    }
    b2[a * E_ + c] = acc;
}

// ---- weight prep: fold + transpose + bf16 (hi/lo where needed) ----
__global__ void k_prep_wgT(const float* __restrict__ Wg, const float* __restrict__ gg,
                           const float* __restrict__ rstd, ushort* __restrict__ WgT) {
    int i = blockIdx.x * 256 + threadIdx.x;
    if (i >= 8 * 128 * 160) return;
    int a = i / (128 * 160), rest = i % (128 * 160);
    int n = rest / 160, k = rest % 160;
    float w = Wg[((size_t)a * 160 + k) * 128 + n] * gg[a * 160 + k] * rstd[a * 160 + k];
    WgT[i] = f2bf(w);
}
__global__ void k_prep_wsT(const float* __restrict__ Ws, const float* __restrict__ sg,
                           const float* __restrict__ rstd,
                           ushort* __restrict__ Th, ushort* __restrict__ Tl) {
    int i = blockIdx.x * 256 + threadIdx.x;
    if (i >= 8 * 128 * 128) return;
    int a = i / (128 * 128), rest = i % (128 * 128);
    int n = rest / 128, k = rest % 128;
    float w = Ws[((size_t)a * 128 + k) * 128 + n] * sg[a * 128 + k] * rstd[a * 160 + k];
    ushort h = f2bf(w);
    Th[i] = h;
    Tl[i] = f2bf(w - bf2f(h));
}
__global__ void k_prep_qkvT(const float* __restrict__ Wq, const float* __restrict__ Wk,
                            const float* __restrict__ Wv, ushort* __restrict__ Tq,
                            ushort* __restrict__ Tk, ushort* __restrict__ Tv) {
    int i = blockIdx.x * 256 + threadIdx.x;
    if (i >= 4 * 32 * 128) return;
    int h = i / (32 * 128), rest = i % (32 * 128);
    int d = rest / 128, e = rest % 128;
    size_t src = ((size_t)h * 128 + e) * 32 + d;
    Tq[i] = f2bf(Wq[src]); Tk[i] = f2bf(Wk[src]); Tv[i] = f2bf(Wv[src]);
}
__global__ void k_prep_f1T(const float* __restrict__ Wf1, ushort* __restrict__ Th,
                           ushort* __restrict__ Tl) {
    int i = blockIdx.x * 256 + threadIdx.x;
    if (i >= 8 * 128 * 256) return;
    int a = i / (128 * 256), rest = i % (128 * 256);
    int n = rest / 256, k = rest % 256;
    float w = Wf1[((size_t)a * 256 + k) * 128 + n];
    ushort h = f2bf(w);
    Th[i] = h;
    if (k >= 128) Tl[((size_t)(a * 128 + n)) * 128 + (k - 128)] = f2bf(w - bf2f(h));
}
__global__ void k_prep_f2T(const float* __restrict__ Wf2, float* __restrict__ T) {
    int i = blockIdx.x * 256 + threadIdx.x;
    if (i >= 8 * 32 * 128) return;
    int a = i / (32 * 128), rest = i % (32 * 128);
    int c = rest / 128, k = rest % 128;
    T[i] = Wf2[((size_t)a * 128 + k) * 32 + c];
}

// ---------------------------------------------------------------------------
// Fused MFMA kernel: 512 threads (8 waves), 16 rows x 8 agents. 12 barriers.
// ---------------------------------------------------------------------------
__global__ __launch_bounds__(512, 1) void k_fused(
    const float* __restrict__ obs, const float* __restrict__ act,
    const ushort* __restrict__ WgT, const float* __restrict__ bg2,
    const ushort* __restrict__ WsTh, const ushort* __restrict__ WsTl,
    const float* __restrict__ bs2,
    const ushort* __restrict__ WqT, const ushort* __restrict__ WkT,
    const ushort* __restrict__ WvT,
    const ushort* __restrict__ Wf1T, const ushort* __restrict__ Wf1Tl,
    const float* __restrict__ bf1,
    const float* __restrict__ Wf2T, const float* __restrict__ bfc2,
    float* __restrict__ out) {
    extern __shared__ char smc[];
    const int tid = threadIdx.x;
    const int b0 = blockIdx.x * NB_;
    const int lane = tid & 63, wv = tid >> 6;
    const int l16 = lane & 15, l4 = lane >> 4;

    // ---- ph0: argmax(act) per row ----
    {
        const int R = tid >> 2, q = tid & 3;
        const int a = R >> 4, r = R & 15;
        const float* ap = act + ((size_t)a * B_ + b0 + r) * 32 + q * 8;
        float bv = -1e30f; int bi = 0;
        #pragma unroll
        for (int u = 0; u < 8; u++) { float x = ap[u]; if (x > bv) { bv = x; bi = q * 8 + u; } }
        #pragma unroll
        for (int off = 1; off < 4; off <<= 1) {
            float ov = __shfl_xor(bv, off, 4);
            int   oi = __shfl_xor(bi, off, 4);
            if (ov > bv || (ov == bv && oi < bi)) { bv = ov; bi = oi; }
        }
        if (q == 0) *(int*)(smc + OFF_BI + R * 4) = bi;
    }

    // ---- ph1: load x -> hi/lo ----
    for (int i = tid; i < 4096; i += 512) {
        const int R = i >> 5, c4 = i & 31;
        const int a = R >> 4, r = R & 15;
        float4 v = *(const float4*)(obs + ((size_t)a * B_ + b0 + r) * 128 + c4 * 4);
        float vv[4] = {v.x, v.y, v.z, v.w};
        #pragma unroll
        for (int j = 0; j < 4; j++) {
            ushort h = f2bf(vv[j]);
            *(ushort*)(smc + XHI(a, r, c4 * 4 + j)) = h;
            *(ushort*)(smc + XLO(a, r, c4 * 4 + j)) = f2bf(vv[j] - bf2f(h));
        }
    }
    for (int i = tid; i < 1024; i += 512) {
        const int R = i >> 3, c4 = i & 7;
        const int a = R >> 4, r = R & 15;
        float4 v = *(const float4*)(act + ((size_t)a * B_ + b0 + r) * 32 + c4 * 4);
        float vv[4] = {v.x, v.y, v.z, v.w};
        #pragma unroll
        for (int j = 0; j < 4; j++)
            *(ushort*)(smc + XHI(a, r, 128 + c4 * 4 + j)) = f2bf(vv[j]);
    }
    __syncthreads();                                           // B1

    const int n = wv * 16 + l16;

    // ---- ph2: e (write now) + s (hold all 8 accs in regs) ----
    f32x4 sacc[8];
    for (int m = 0; m < 8; m++) {
        f32x4 ea = (f32x4){0.f, 0.f, 0.f, 0.f};
        f32x4 sa = (f32x4){0.f, 0.f, 0.f, 0.f};
        #pragma unroll
        for (int kc = 0; kc < 4; kc++) {
            const int kof = kc * 32 + l4 * 8;
            s16x8 ah = *(const s16x8*)(smc + XHI(m, l16, kof));
            s16x8 al = *(const s16x8*)(smc + XLO(m, l16, kof));
            s16x8 bg = *(const s16x8*)(WgT + ((size_t)m * 128 + n) * 160 + kof);
            s16x8 bh = *(const s16x8*)(WsTh + ((size_t)m * 128 + n) * 128 + kof);
            s16x8 bl = *(const s16x8*)(WsTl + ((size_t)m * 128 + n) * 128 + kof);
            ea = MFMA16(ah, bg, ea);
            sa = MFMA16(ah, bh, sa);
            sa = MFMA16(al, bh, sa);
            sa = MFMA16(ah, bl, sa);
        }
        {   // e act tail (kc=4)
            const int kof = 128 + l4 * 8;
            s16x8 ah = *(const s16x8*)(smc + XHI(m, l16, kof));
            s16x8 bg = *(const s16x8*)(WgT + ((size_t)m * 128 + n) * 160 + kof);
            ea = MFMA16(ah, bg, ea);
        }
        const float bb = bg2[m * 128 + n];
        #pragma unroll
        for (int j = 0; j < 4; j++)
            *(ushort*)(smc + EA(m * 16 + l4 * 4 + j, n)) = f2bf(lrelu(ea[j] + bb));
        sacc[m] = sa;
    }
    __syncthreads();                                           // B2 (all x reads done)
    #pragma unroll
    for (int m = 0; m < 8; m++) {
        const float bb = bs2[m * 128 + n];
        #pragma unroll
        for (int j = 0; j < 4; j++) {
            float s = lrelu(sacc[m][j] + bb);
            ushort h = f2bf(s);
            *(ushort*)(smc + SHI(m, l4 * 4 + j, n)) = h;
            *(ushort*)(smc + SLO(m, l4 * 4 + j, n)) = f2bf(s - bf2f(h));
        }
    }
    __syncthreads();                                           // B3

    // q/k for one head: wave wv owns agent wv, cols d 0..31 (2 tiles)
    auto qk_head = [&](int h) {
        #pragma unroll
        for (int dt = 0; dt < 2; dt++) {
            f32x4 aq = (f32x4){0.f, 0.f, 0.f, 0.f};
            f32x4 ak = (f32x4){0.f, 0.f, 0.f, 0.f};
            const int d = dt * 16 + l16;
            const ushort* wq = WqT + ((size_t)(h * 32 + d)) * 128;
            const ushort* wk = WkT + ((size_t)(h * 32 + d)) * 128;
            #pragma unroll
            for (int kc = 0; kc < 4; kc++) {
                const int kof = kc * 32 + l4 * 8;
                s16x8 a  = *(const s16x8*)(smc + EA(wv * 16 + l16, kof));
                aq = MFMA16(a, *(const s16x8*)(wq + kof), aq);
                ak = MFMA16(a, *(const s16x8*)(wk + kof), ak);
            }
            #pragma unroll
            for (int j = 0; j < 4; j++) {
                const int r = l4 * 4 + j;
                *(ushort*)(smc + QHA(wv, r, d >> 3) + (d & 7) * 2) = f2bf(aq[j]);
                *(ushort*)(smc + KHA(wv, r, d >> 3) + (d & 7) * 2) = f2bf(ak[j]);
            }
        }
    };

    // ---- ph3: v (all heads) + qk(head 0) ----
    {
        f32x4 acc[8];
        #pragma unroll
        for (int m = 0; m < 8; m++) acc[m] = (f32x4){0.f, 0.f, 0.f, 0.f};
        const ushort* wp = WvT + ((size_t)n) * 128;   // n = h*32+d global col
        #pragma unroll
        for (int kc = 0; kc < 4; kc++) {
            const int kof = kc * 32 + l4 * 8;
            s16x8 b = *(const s16x8*)(wp + kof);
            #pragma unroll
            for (int m = 0; m < 8; m++) {
                s16x8 a = *(const s16x8*)(smc + EA(m * 16 + l16, kof));
                acc[m] = MFMA16(a, b, acc[m]);
            }
        }
        #pragma unroll
        for (int m = 0; m < 8; m++)
            #pragma unroll
            for (int j = 0; j < 4; j++)
                *(ushort*)(smc + VA2(m * 16 + l4 * 4 + j, n)) = f2bf(lrelu(acc[m][j]));
    }
    qk_head(0);
    __syncthreads();                                           // B4

    // ---- ph4: per head: alpha dots; prefetch next head's q/k ----
    for (int h = 0; h < 4; h++) {
        #pragma unroll
        for (int p = 0; p < 2; p++) {
            const int e = p * 512 + tid;
            const int j = e & 7, i = (e >> 3) & 7, r = e >> 6;
            float dot = 0.f;
            #pragma unroll
            for (int ch = 0; ch < 4; ch++) {
                s16x8 qv = *(const s16x8*)(smc + QHA(i, r, ch));
                s16x8 kv = *(const s16x8*)(smc + KHA(j, r, ch));
                #pragma unroll
                for (int u = 0; u < 8; u++)
                    dot += bf2f((ushort)qv[u]) * bf2f((ushort)kv[u]);
            }
            *(ushort*)(smc + AL2(h, r, i, j)) =
                (i == j) ? (ushort)0 : f2bf(dot * 0.17677669529663687f);
        }
        __syncthreads();                                       // alpha(h) visible
        if (h < 3) {
            qk_head(h + 1);
            __syncthreads();                                   // qk(h+1) visible
        }
    }

    // ---- ph5: xi (all agents) -> EA region (e dead) ----
    {
        const int c = tid & 127, rg = tid >> 7;
        const int h = c >> 5;
        for (int rr = 0; rr < 32; rr++) {
            const int R = rg * 32 + rr;
            const int a = R >> 4, r = R & 15;
            s16x8 av = *(const s16x8*)(smc + AL2(h, r, a, 0));
            float acc = 0.f;
            #pragma unroll
            for (int j = 0; j < 8; j++)
                acc += bf2f((ushort)av[j]) * bf2f(*(const ushort*)(smc + VA2(j * 16 + r, c)));
            *(ushort*)(smc + EA(R, c)) = f2bf(acc);
        }
    }
    __syncthreads();                                           // B(xi)

    // ---- ph6: f1 per wave (agent wv, full N=128) + fused out-dot ----
    {
        const int m = wv;
        float ps[4] = {0.f, 0.f, 0.f, 0.f};
        int bis[4];
        #pragma unroll
        for (int j = 0; j < 4; j++)
            bis[j] = *(const int*)(smc + OFF_BI + (m * 16 + l4 * 4 + j) * 4);
        for (int nt = 0; nt < 8; nt++) {
            const int nn = nt * 16 + l16;
            f32x4 acc = (f32x4){0.f, 0.f, 0.f, 0.f};
            const ushort* w1  = Wf1T  + ((size_t)m * 128 + nn) * 256;
            const ushort* w1l = Wf1Tl + ((size_t)m * 128 + nn) * 128;
            #pragma unroll
            for (int kc = 0; kc < 4; kc++) {
                const int kof = kc * 32 + l4 * 8;
                s16x8 a = *(const s16x8*)(smc + EA(m * 16 + l16, kof));
                acc = MFMA16(a, *(const s16x8*)(w1 + kof), acc);
            }
            #pragma unroll
            for (int kc = 0; kc < 4; kc++) {
                const int kof = kc * 32 + l4 * 8;
                s16x8 ah = *(const s16x8*)(smc + SHI(m, l16, kof));
                s16x8 al = *(const s16x8*)(smc + SLO(m, l16, kof));
                s16x8 bh = *(const s16x8*)(w1 + 128 + kof);
                s16x8 bl = *(const s16x8*)(w1l + kof);
                acc = MFMA16(ah, bh, acc);
                acc = MFMA16(al, bh, acc);
                acc = MFMA16(ah, bl, acc);
            }
            const float bb = bf1[m * 128 + nn];
            #pragma unroll
            for (int j = 0; j < 4; j++) {
                const float w2 = Wf2T[((size_t)m * 32 + bis[j]) * 128 + nn];
                ps[j] += lrelu(acc[j] + bb) * w2;
            }
        }
        #pragma unroll
        for (int off = 1; off < 16; off <<= 1)
            #pragma unroll
            for (int j = 0; j < 4; j++) ps[j] += __shfl_xor(ps[j], off, 16);
        if (l16 == 0)
            #pragma unroll
            for (int j = 0; j < 4; j++)
                out[(size_t)m * B_ + b0 + l4 * 4 + j] = ps[j] + bfc2[m * 32 + bis[j]];
    }
}

// ---------------------------------------------------------------------------
extern "C" void kernel_launch(void* const* d_in, const int* in_sizes, int n_in,
                              void* d_out, int out_size, void* d_ws, size_t ws_size,
                              hipStream_t stream) {
    const float* obs     = (const float*)d_in[0];
    const float* act     = (const float*)d_in[1];
    const float* g_gamma = (const float*)d_in[2];
    const float* g_beta  = (const float*)d_in[3];
    const float* Wg      = (const float*)d_in[4];
    const float* bg      = (const float*)d_in[5];
    const float* s_gamma = (const float*)d_in[6];
    const float* s_beta  = (const float*)d_in[7];
    const float* Ws      = (const float*)d_in[8];
    const float* bs      = (const float*)d_in[9];
    const float* Wq      = (const float*)d_in[10];
    const float* Wk      = (const float*)d_in[11];
    const float* Wv      = (const float*)d_in[12];
    const float* Wf1     = (const float*)d_in[13];
    const float* bf1     = (const float*)d_in[14];
    const float* Wf2     = (const float*)d_in[15];
    const float* bf2     = (const float*)d_in[16];

    if (ws_size < (size_t)WSB_TOTAL) return;

    (void)hipFuncSetAttribute((const void*)k_fused,
                              hipFuncAttributeMaxDynamicSharedMemorySize, SMEM_BYTES);

    char* ws = (char*)d_ws;
    float*  gsum  = (float*)(ws + WSB_GSUM);
    float*  gsq   = (float*)(ws + WSB_GSQ);
    float*  mean  = (float*)(ws + WSB_MEAN);
    float*  rstd  = (float*)(ws + WSB_RSTD);
    float*  bg2   = (float*)(ws + WSB_BG2);
    float*  bs2   = (float*)(ws + WSB_BS2);
    ushort* WgT   = (ushort*)(ws + WSB_WGT);
    ushort* WsTh  = (ushort*)(ws + WSB_WSTH);
    ushort* WsTl  = (ushort*)(ws + WSB_WSTL);
    ushort* WqT   = (ushort*)(ws + WSB_WQT);
    ushort* WkT   = (ushort*)(ws + WSB_WKT);
    ushort* WvT   = (ushort*)(ws + WSB_WVT);
    ushort* Wf1T  = (ushort*)(ws + WSB_WF1T);
    ushort* Wf1Tl = (ushort*)(ws + WSB_WF1TL);
    float*  Wf2T  = (float*)(ws + WSB_WF2T);

    k_zero<<<10, 256, 0, stream>>>(gsum);
    k_stats<<<dim3(256, A_), 256, 0, stream>>>(obs, act, gsum, gsq);
    k_finalize<<<5, 256, 0, stream>>>(gsum, gsq, mean, rstd);
    k_fold_bias<<<A_, 128, 0, stream>>>(Wg, g_gamma, g_beta, bg, mean, rstd, bg2, F_);
    k_fold_bias<<<A_, 128, 0, stream>>>(Ws, s_gamma, s_beta, bs, mean, rstd, bs2, OBS_);
    k_prep_wgT<<<640, 256, 0, stream>>>(Wg, g_gamma, rstd, WgT);
    k_prep_wsT<<<512, 256, 0, stream>>>(Ws, s_gamma, rstd, WsTh, WsTl);
    k_prep_qkvT<<<64, 256, 0, stream>>>(Wq, Wk, Wv, WqT, WkT, WvT);
    k_prep_f1T<<<1024, 256, 0, stream>>>(Wf1, Wf1T, Wf1Tl);
    k_prep_f2T<<<128, 256, 0, stream>>>(Wf2, Wf2T);
    k_fused<<<B_ / NB_, 512, SMEM_BYTES, stream>>>(
        obs, act, WgT, bg2, WsTh, WsTl, bs2, WqT, WkT, WvT,
        Wf1T, Wf1Tl, bf1, Wf2T, bf2, (float*)d_out);
}